// Round 6
// baseline (1398.771 us; speedup 1.0000x reference)
//
#include <hip/hip_runtime.h>
#include <cstdint>

#define NLAYER 4
#define DMODEL 1024
#define NHEAD 16
#define DHEAD 64
#define DINNER 4096
#define QLEN 512
#define MLEN 512
#define KLEN (QLEN + MLEN)
#define BATCH 4
#define ND (NHEAD * DHEAD)

typedef unsigned short u16;
typedef __attribute__((ext_vector_type(8))) short short8;
typedef __attribute__((ext_vector_type(4))) float f32x4;
typedef __attribute__((address_space(1))) const unsigned int guint;
typedef __attribute__((address_space(3))) unsigned int luint;

__device__ __forceinline__ u16 f2b(float x) {
  unsigned u = __builtin_bit_cast(unsigned, x);
  return (u16)((u + 0x7fffu + ((u >> 16) & 1u)) >> 16);
}
__device__ __forceinline__ float b2f(u16 h) {
  return __builtin_bit_cast(float, (unsigned)h << 16);
}

// ---------------- f32 -> bf16 bulk convert ----------------
__global__ __launch_bounds__(256) void conv_bf16(
    const float* __restrict__ s, u16* __restrict__ d, int n8)
{
  const int i = blockIdx.x * 256 + threadIdx.x;
  if (i >= n8) return;
  const float4 a = ((const float4*)s)[2 * i], b = ((const float4*)s)[2 * i + 1];
  union { u16 u[8]; float4 v; } p;
  p.u[0] = f2b(a.x); p.u[1] = f2b(a.y); p.u[2] = f2b(a.z); p.u[3] = f2b(a.w);
  p.u[4] = f2b(b.x); p.u[5] = f2b(b.y); p.u[6] = f2b(b.z); p.u[7] = f2b(b.w);
  ((float4*)d)[i] = p.v;
}

// ---------------- embedding gather ----------------
__global__ __launch_bounds__(256) void embed_kernel(
    const int* __restrict__ tok, const float* __restrict__ emb,
    float* __restrict__ h, u16* __restrict__ hb)
{
  const int q = blockIdx.x, b = blockIdx.y, t = threadIdx.x;
  const int id = tok[b * QLEN + q];
  const float4 v = ((const float4*)(emb + (size_t)id * DMODEL))[t];
  const size_t row = (size_t)q * BATCH + b;
  ((float4*)(h + row * DMODEL))[t] = v;
  union { u16 u[4]; float2 f; } p;
  p.u[0] = f2b(v.x); p.u[1] = f2b(v.y); p.u[2] = f2b(v.z); p.u[3] = f2b(v.w);
  *(float2*)(hb + row * DMODEL + t * 4) = p.f;
}

// ---------------- sinusoidal pos emb (bf16 out) ----------------
__global__ __launch_bounds__(256) void posemb_kernel(u16* __restrict__ pe)
{
  const int k = blockIdx.x, t = threadIdx.x;
  const float pos = (float)(KLEN - 1 - k);
  for (int i = t; i < DMODEL / 2; i += 256) {
    const float inv_freq = powf(10000.0f, -(float)(2 * i) / (float)DMODEL);
    const float a = pos * inv_freq;
    pe[(size_t)k * DMODEL + i] = f2b(sinf(a));
    pe[(size_t)k * DMODEL + DMODEL / 2 + i] = f2b(cosf(a));
  }
}

// ======== mgemm2: m97-style NT GEMM with global_load_lds + XOR swizzle ========
// C[M,N] = A @ B^T. 128x128 tile, BK=64, 4 waves (2x2). A rows < splitRow from
// A0, >= splitRow from A1 (A1 may be null). Linear LDS [128][64] u16; global
// source pre-swizzled chunk g = c ^ (row&7); ds_read applies same XOR.
template<int OUTBF, int RELU, int BIAS>
__global__ __launch_bounds__(256) void mgemm2(
    const u16* __restrict__ A0, const u16* __restrict__ A1, int splitRow,
    const u16* __restrict__ B, void* __restrict__ Cp,
    const float* __restrict__ bias, int Kd, long sa, long sb, long sc)
{
  __shared__ u16 As[128][64];
  __shared__ u16 Bs[128][64];
  const int bm = blockIdx.x * 128, bn = blockIdx.y * 128;
  const int t = threadIdx.x, wave = t >> 6, lane = t & 63;
  const int wm = (wave >> 1) * 64, wn = (wave & 1) * 64;
  const int lrow = lane & 15, lk = lane >> 4;
  const int srow0 = wave * 32 + (lane >> 3);  // +c*8 per chunk
  const int sg = lane & 7;
  // per-lane global row pointers for the 4 chunks (row fixed across K-steps)
  const u16* arow[4];
  const u16* brow[4];
  int gsw[4];
#pragma unroll
  for (int c = 0; c < 4; ++c) {
    const int row = srow0 + c * 8;
    gsw[c] = (sg ^ (row & 7)) * 8;
    const int ga = bm + row;
    arow[c] = (A1 != nullptr && ga >= splitRow) ? (A1 + (size_t)(ga - splitRow) * sa)
                                                : (A0 + (size_t)ga * sa);
    brow[c] = B + (size_t)(bn + row) * sb;
  }
  f32x4 acc[4][4] = {};
  for (int k0 = 0; k0 < Kd; k0 += 64) {
    __syncthreads();
#pragma unroll
    for (int c = 0; c < 4; ++c) {
      __builtin_amdgcn_global_load_lds((guint*)(arow[c] + k0 + gsw[c]),
                                       (luint*)&As[wave * 32 + c * 8][0], 16, 0, 0);
      __builtin_amdgcn_global_load_lds((guint*)(brow[c] + k0 + gsw[c]),
                                       (luint*)&Bs[wave * 32 + c * 8][0], 16, 0, 0);
    }
    __syncthreads();
#pragma unroll
    for (int ks = 0; ks < 2; ++ks) {
      short8 af[4], bf[4];
#pragma unroll
      for (int x = 0; x < 4; ++x) {
        const int ra = wm + x * 16 + lrow;
        const int rb = wn + x * 16 + lrow;
        af[x] = *(const short8*)((const u16*)As + ra * 64 + (((ks * 4 + lk) ^ (ra & 7)) * 8));
        bf[x] = *(const short8*)((const u16*)Bs + rb * 64 + (((ks * 4 + lk) ^ (rb & 7)) * 8));
      }
#pragma unroll
      for (int mi = 0; mi < 4; ++mi)
#pragma unroll
        for (int ni = 0; ni < 4; ++ni)
          acc[mi][ni] = __builtin_amdgcn_mfma_f32_16x16x32_bf16(af[mi], bf[ni], acc[mi][ni], 0, 0, 0);
    }
  }
  const size_t row0 = bm + wm + lk * 4;
  const size_t col0 = bn + wn + lrow;
#pragma unroll
  for (int mi = 0; mi < 4; ++mi)
#pragma unroll
    for (int r = 0; r < 4; ++r) {
      const size_t row = row0 + mi * 16 + r;
#pragma unroll
      for (int ni = 0; ni < 4; ++ni) {
        float v = acc[mi][ni][r];
        if (BIAS) v += bias[col0 + ni * 16];
        if (RELU) v = fmaxf(v, 0.0f);
        if (OUTBF) ((u16*)Cp)[row * sc + col0 + ni * 16] = f2b(v);
        else       ((float*)Cp)[row * sc + col0 + ni * 16] = v;
      }
    }
}

// ---------------- old flexible MFMA NT GEMM (kept for BD, z-batched) ----------------
template<int MF, int OUTBF, int RELU, int BIAS>
__global__ __launch_bounds__(256) void mgemm(
    const u16* __restrict__ A, const u16* __restrict__ B, void* __restrict__ Cp,
    const float* __restrict__ bias, int Kd,
    long sa, long sb, long sc,
    long azb, long azn, long bzb, long bzn, long czb, long czn)
{
  constexpr int BM = MF * 32;
  __shared__ u16 As[BM][40];
  __shared__ u16 Bs[128][40];
  const int z = blockIdx.z, zb = z & 3, zn = z >> 2;
  A += (size_t)zb * azb + (size_t)zn * azn;
  B += (size_t)zb * bzb + (size_t)zn * bzn;
  const size_t bm = (size_t)blockIdx.x * BM, bn = (size_t)blockIdx.y * 128;
  const int t = threadIdx.x;
  const int wave = t >> 6, lane = t & 63;
  const int wm = (wave >> 1) * (MF * 16), wn = (wave & 1) * 64;
  const int lrow = lane & 15, lk = lane >> 4;
  const int srow = t >> 2, skc = (t & 3) * 8;
  const u16* Ap = A + (bm + srow) * sa + skc;
  const u16* Bp = B + (bn + srow) * sb + skc;
  f32x4 acc[MF][4] = {};
  for (int k0 = 0; k0 < Kd; k0 += 32) {
    float4 a0, a1;
    a0 = *(const float4*)(Ap + k0);
    if (MF == 4) a1 = *(const float4*)(Ap + 64 * sa + k0);
    const float4 b0 = *(const float4*)(Bp + k0);
    const float4 b1 = *(const float4*)(Bp + 64 * sb + k0);
    __syncthreads();
    if (srow < BM) *(float4*)&As[srow][skc] = a0;
    if (MF == 4) *(float4*)&As[(srow + 64) & (BM - 1)][skc] = a1;
    *(float4*)&Bs[srow][skc] = b0;
    *(float4*)&Bs[srow + 64][skc] = b1;
    __syncthreads();
    short8 af[MF], bf[4];
#pragma unroll
    for (int x = 0; x < MF; ++x) af[x] = *(const short8*)&As[wm + x * 16 + lrow][lk * 8];
#pragma unroll
    for (int x = 0; x < 4; ++x) bf[x] = *(const short8*)&Bs[wn + x * 16 + lrow][lk * 8];
#pragma unroll
    for (int mi = 0; mi < MF; ++mi)
#pragma unroll
      for (int ni = 0; ni < 4; ++ni)
        acc[mi][ni] = __builtin_amdgcn_mfma_f32_16x16x32_bf16(af[mi], bf[ni], acc[mi][ni], 0, 0, 0);
  }
  const size_t row0 = bm + wm + lk * 4;
  const size_t col0 = bn + wn + lrow;
#pragma unroll
  for (int mi = 0; mi < MF; ++mi)
#pragma unroll
    for (int r = 0; r < 4; ++r) {
      const size_t row = row0 + mi * 16 + r;
#pragma unroll
      for (int ni = 0; ni < 4; ++ni) {
        float v = acc[mi][ni][r];
        if (BIAS) v += bias[col0 + ni * 16];
        if (RELU) v = fmaxf(v, 0.0f);
        if (OUTBF) ((u16*)Cp + (size_t)zb * czb + (size_t)zn * czn)[row * sc + col0 + ni * 16] = f2b(v);
        else       ((float*)Cp + (size_t)zb * czb + (size_t)zn * czn)[row * sc + col0 + ni * 16] = v;
      }
    }
}

// ---------------- qa/qb prep ----------------
__global__ __launch_bounds__(256) void qprep_kernel(
    const u16* __restrict__ qkvb, const float* __restrict__ rwb,
    const float* __restrict__ rrb, u16* __restrict__ qa, u16* __restrict__ qb)
{
  const int i = blockIdx.x, b = blockIdx.y, t = threadIdx.x;
  const int c = t * 4;
  const size_t src = ((size_t)(QLEN + i) * BATCH + b) * (3 * ND) + c;
  const size_t dst = ((size_t)b * QLEN + i) * ND + c;
  union { u16 u[4]; float2 f; } qi, oa, ob;
  qi.f = *(const float2*)(qkvb + src);
#pragma unroll
  for (int e = 0; e < 4; ++e) {
    const float q = b2f(qi.u[e]);
    oa.u[e] = f2b(q + rwb[c + e]);
    ob.u[e] = f2b(q + rrb[c + e]);
  }
  *(float2*)(qa + dst) = oa.f;
  *(float2*)(qb + dst) = ob.f;
}

// ---------------- V transpose: qkv V -> Vt[b][n][d][j] ----------------
__global__ __launch_bounds__(256) void vtrans_kernel(
    const u16* __restrict__ qkvb, u16* __restrict__ Vt)
{
  __shared__ u16 T[64][72];
  const int j0 = blockIdx.x * 64;
  const int bn = blockIdx.y, b = bn >> 4, n = bn & 15;
  const int t = threadIdx.x;
  const int jl = t >> 3, ch = t & 7;
#pragma unroll
  for (int p = 0; p < 2; ++p) {
    const int jj = p * 32 + jl;
    const float4 v = *(const float4*)(qkvb + ((size_t)(j0 + jj) * BATCH + b) * (3 * ND)
                                      + 2 * ND + n * 64 + ch * 8);
    *(float4*)&T[jj][ch * 8] = v;
  }
  __syncthreads();
#pragma unroll
  for (int p = 0; p < 2; ++p) {
    const int dd = p * 32 + jl;
    union { u16 u[8]; float4 v; } o;
#pragma unroll
    for (int e = 0; e < 8; ++e) o.u[e] = T[ch * 8 + e][dd];
    *(float4*)(Vt + ((size_t)(b * 16 + n) * 64 + dd) * 1024 + j0 + ch * 8) = o.v;
  }
}

// ---------------- fused flash attention: AC + shifted-BD(bf16) + softmax + PV ----------
__global__ __launch_bounds__(256) void flash_attn(
    const u16* __restrict__ qa, const u16* __restrict__ qkvb,
    const u16* __restrict__ Vt, const u16* __restrict__ BD,
    u16* __restrict__ O)
{
  __shared__ u16 qs[64][72];
  __shared__ u16 ks[64][72];
  __shared__ u16 vs[64][72];
  __shared__ u16 ps[4][16][72];
  const int i0 = blockIdx.x * 64;
  const int n = blockIdx.y, b = blockIdx.z;
  const int t = threadIdx.x, wave = t >> 6, lane = t & 63;
  const int lrow = lane & 15, lk = lane >> 4;
  const int sr = t >> 2, sc = (t & 3) * 8;
  {
    const u16* src = qa + ((size_t)b * QLEN + i0 + sr) * ND + n * 64;
    *(float4*)&qs[sr][sc] = *(const float4*)(src + sc);
    *(float4*)&qs[sr][sc + 32] = *(const float4*)(src + sc + 32);
  }
  const u16* bd = BD + ((size_t)(n * 4 + b) * QLEN + i0) * 1024;
  f32x4 o[4] = {};
  float m[4] = {-INFINITY, -INFINITY, -INFINITY, -INFINITY};
  float l[4] = {0.0f, 0.0f, 0.0f, 0.0f};
  const int ntiles = blockIdx.x + 9;
  for (int jt = 0; jt < ntiles; ++jt) {
    const int j0 = jt * 64;
    const u16* ksrc = qkvb + ((size_t)(j0 + sr) * BATCH + b) * (3 * ND) + ND + n * 64;
    const u16* vsrc = Vt + ((size_t)(b * 16 + n) * 64 + sr) * 1024 + j0;
    const float4 k0v = *(const float4*)(ksrc + sc);
    const float4 k1v = *(const float4*)(ksrc + sc + 32);
    const float4 v0v = *(const float4*)(vsrc + sc);
    const float4 v1v = *(const float4*)(vsrc + sc + 32);
    __syncthreads();
    *(float4*)&ks[sr][sc] = k0v;  *(float4*)&ks[sr][sc + 32] = k1v;
    *(float4*)&vs[sr][sc] = v0v;  *(float4*)&vs[sr][sc + 32] = v1v;
    __syncthreads();
    f32x4 s[4] = {};
    const short8 aq0 = *(const short8*)&qs[wave * 16 + lrow][lk * 8];
    const short8 aq1 = *(const short8*)&qs[wave * 16 + lrow][32 + lk * 8];
#pragma unroll
    for (int nf = 0; nf < 4; ++nf) {
      const short8 b0 = *(const short8*)&ks[nf * 16 + lrow][lk * 8];
      const short8 b1 = *(const short8*)&ks[nf * 16 + lrow][32 + lk * 8];
      s[nf] = __builtin_amdgcn_mfma_f32_16x16x32_bf16(aq0, b0, s[nf], 0, 0, 0);
      s[nf] = __builtin_amdgcn_mfma_f32_16x16x32_bf16(aq1, b1, s[nf], 0, 0, 0);
    }
    float sv[4][4];
#pragma unroll
    for (int nf = 0; nf < 4; ++nf)
#pragma unroll
      for (int r = 0; r < 4; ++r) {
        const int il = wave * 16 + lk * 4 + r;
        const int ig = i0 + il;
        const int jg = j0 + nf * 16 + lrow;
        int p = jg - ig + 511;
        p = p > 1023 ? 1023 : p;
        const float bdv = b2f(bd[(size_t)il * 1024 + p]);
        const float val = (s[nf][r] + bdv) * 0.125f;
        sv[nf][r] = (jg <= ig + MLEN) ? val : -INFINITY;
      }
#pragma unroll
    for (int r = 0; r < 4; ++r) {
      float mt = fmaxf(fmaxf(sv[0][r], sv[1][r]), fmaxf(sv[2][r], sv[3][r]));
#pragma unroll
      for (int dx = 1; dx < 16; dx <<= 1) mt = fmaxf(mt, __shfl_xor(mt, dx));
      const float mnew = fmaxf(m[r], mt);
      const float alpha = __expf(m[r] - mnew);
      float ls = 0.0f;
#pragma unroll
      for (int nf = 0; nf < 4; ++nf) {
        const float pv = __expf(sv[nf][r] - mnew);
        sv[nf][r] = pv;
        ls += pv;
      }
#pragma unroll
      for (int dx = 1; dx < 16; dx <<= 1) ls += __shfl_xor(ls, dx);
      l[r] = l[r] * alpha + ls;
      m[r] = mnew;
#pragma unroll
      for (int nf = 0; nf < 4; ++nf) o[nf][r] *= alpha;
    }
#pragma unroll
    for (int nf = 0; nf < 4; ++nf)
#pragma unroll
      for (int r = 0; r < 4; ++r)
        ps[wave][lk * 4 + r][nf * 16 + lrow] = f2b(sv[nf][r]);
    asm volatile("s_waitcnt lgkmcnt(0)" ::: "memory");
    __builtin_amdgcn_sched_barrier(0);
    const short8 pa0 = *(const short8*)&ps[wave][lrow][lk * 8];
    const short8 pa1 = *(const short8*)&ps[wave][lrow][32 + lk * 8];
#pragma unroll
    for (int nf = 0; nf < 4; ++nf) {
      const short8 b0 = *(const short8*)&vs[nf * 16 + lrow][lk * 8];
      const short8 b1 = *(const short8*)&vs[nf * 16 + lrow][32 + lk * 8];
      o[nf] = __builtin_amdgcn_mfma_f32_16x16x32_bf16(pa0, b0, o[nf], 0, 0, 0);
      o[nf] = __builtin_amdgcn_mfma_f32_16x16x32_bf16(pa1, b1, o[nf], 0, 0, 0);
    }
  }
#pragma unroll
  for (int r = 0; r < 4; ++r) {
    const float inv = 1.0f / l[r];
    const size_t ig = i0 + wave * 16 + lk * 4 + r;
#pragma unroll
    for (int nf = 0; nf < 4; ++nf)
      O[(ig * BATCH + b) * ND + n * 64 + nf * 16 + lrow] = f2b(o[nf][r] * inv);
  }
}

// ---------------- fused residual + LayerNorm ----------------
__global__ __launch_bounds__(256) void ln_residual_kernel(
    float* __restrict__ h, u16* __restrict__ hb, const float* __restrict__ delta,
    const float* __restrict__ g, const float* __restrict__ bb)
{
  const int row = blockIdx.x, t = threadIdx.x;
  __shared__ float xs[DMODEL];
  __shared__ float red[256];
  float s = 0.0f;
  for (int d = t; d < DMODEL; d += 256) {
    const float v = h[(size_t)row * DMODEL + d] + delta[(size_t)row * DMODEL + d];
    xs[d] = v;
    s += v;
  }
  red[t] = s;
  __syncthreads();
  for (int w = 128; w > 0; w >>= 1) {
    if (t < w) red[t] += red[t + w];
    __syncthreads();
  }
  const float mean = red[0] * (1.0f / DMODEL);
  __syncthreads();
  float vs = 0.0f;
  for (int d = t; d < DMODEL; d += 256) {
    const float dv = xs[d] - mean;
    vs = fmaf(dv, dv, vs);
  }
  red[t] = vs;
  __syncthreads();
  for (int w = 128; w > 0; w >>= 1) {
    if (t < w) red[t] += red[t + w];
    __syncthreads();
  }
  const float rstd = rsqrtf(red[0] * (1.0f / DMODEL) + 1e-5f);
  for (int d = t; d < DMODEL; d += 256) {
    const float o = (xs[d] - mean) * rstd * g[d] + bb[d];
    h[(size_t)row * DMODEL + d] = o;
    hb[(size_t)row * DMODEL + d] = f2b(o);
  }
}

// ---------------- output transpose ----------------
__global__ __launch_bounds__(256) void out_kernel(
    const float* __restrict__ h, float* __restrict__ out)
{
  const int q = blockIdx.x, b = blockIdx.y, t = threadIdx.x;
  const float4* src = (const float4*)(h + ((size_t)q * BATCH + b) * DMODEL);
  float4* dst = (float4*)(out + ((size_t)b * QLEN + q) * DMODEL);
  dst[t] = src[t];
}

extern "C" void kernel_launch(void* const* d_in, const int* in_sizes, int n_in,
                              void* d_out, int out_size, void* d_ws, size_t ws_size,
                              hipStream_t stream)
{
  const int*   tok  = (const int*)d_in[0];
  const float* mems = (const float*)d_in[1];
  const float* wemb = (const float*)d_in[2];
  const float* qkvw = (const float*)d_in[3];
  const float* ow   = (const float*)d_in[4];
  const float* rw   = (const float*)d_in[5];
  const float* rwb  = (const float*)d_in[6];
  const float* rrb  = (const float*)d_in[7];
  const float* ln1g = (const float*)d_in[8];
  const float* ln1b = (const float*)d_in[9];
  const float* ffw1 = (const float*)d_in[10];
  const float* ffb1 = (const float*)d_in[11];
  const float* ffw2 = (const float*)d_in[12];
  const float* ffb2 = (const float*)d_in[13];
  const float* ln2g = (const float*)d_in[14];
  const float* ln2b = (const float*)d_in[15];

  float* h      = (float*)d_ws;               // [2048][1024] f32
  u16* S        = (u16*)(h + 2097152);        // BDraw [64][512][1024] bf16 (64 MB)
  float* tmp    = (float*)S;                  // alias (BDraw dead after flash)
  u16* h_bf     = S + 33554432;
  u16* qkv_bf   = h_bf + 2097152;             // [4096][3072]
  u16* ffh_bf   = qkv_bf;                     // alias (qkv dead after attention)
  u16* pe_bf    = qkv_bf + 12582912;
  u16* rb_bf    = pe_bf + 1048576;
  u16* qa_bf    = rb_bf + 1048576;            // [4][512][1024]
  u16* qb_bf    = qa_bf + 2097152;
  u16* Vt       = qb_bf + 2097152;            // [4][16][64][1024]
  u16* vec_bf   = Vt + 4194304;               // [2048][1024]
  u16* mems_bf  = vec_bf + 2097152;           // [4][2048][1024]
  u16* wq = mems_bf + 8388608;                // [4][3072][1024]
  u16* wo = wq + 12582912;                    // [4][1024][1024]
  u16* wr = wo + 4194304;                     // [4][1024][1024]
  u16* w1 = wr + 4194304;                     // [4][4096][1024]
  u16* w2 = w1 + 16777216;                    // [4][1024][4096]

  embed_kernel<<<dim3(QLEN, BATCH), 256, 0, stream>>>(tok, wemb, h, h_bf);
  posemb_kernel<<<KLEN, 256, 0, stream>>>(pe_bf);

#define CONV(src, dst, n) conv_bf16<<<(n) / 2048, 256, 0, stream>>>(src, dst, (n) / 8)
  // all layers' weights + mems converted once
  CONV(mems, mems_bf, 8388608);
  CONV(qkvw, wq, 12582912);
  CONV(ow,   wo, 4194304);
  CONV(rw,   wr, 4194304);
  CONV(ffw1, w1, 16777216);
  CONV(ffw2, w2, 16777216);

  for (int l = 0; l < NLAYER; ++l) {
    // qkv = cat(mems_bf[l], h_bf) @ qkv_w^T  (bf16 out)
    mgemm2<1, 0, 0><<<dim3(32, 24), 256, 0, stream>>>(
        mems_bf + (size_t)l * 2097152, h_bf, 2048,
        wq + (size_t)l * 3145728, qkv_bf, nullptr, 1024, 1024, 1024, 3072);
    // r = pe @ r_w^T  (bf16 out)
    mgemm2<1, 0, 0><<<dim3(8, 8), 256, 0, stream>>>(
        pe_bf, nullptr, 0, wr + (size_t)l * 1048576, rb_bf, nullptr,
        1024, 1024, 1024, 1024);

    qprep_kernel<<<dim3(QLEN, BATCH), 256, 0, stream>>>(
        qkv_bf, rwb + (size_t)l * ND, rrb + (size_t)l * ND, qa_bf, qb_bf);
    vtrans_kernel<<<dim3(16, 64), 256, 0, stream>>>(qkv_bf, Vt);

    // BDraw[n*4+b][i][s] = qb_i . r_s   (bf16 out, one dispatch)
    mgemm<4, 1, 0, 0><<<dim3(4, 8, 64), 256, 0, stream>>>(
        qb_bf, rb_bf, S, nullptr, 64,
        1024, 1024, 1024, 524288, 64, 0, 64, 524288, 2097152);

    flash_attn<<<dim3(8, 16, 4), 256, 0, stream>>>(qa_bf, qkv_bf, Vt, S, vec_bf);

    // o-proj (f32 out into tmp)
    mgemm2<0, 0, 0><<<dim3(16, 8), 256, 0, stream>>>(
        vec_bf, nullptr, 0, wo + (size_t)l * 1048576, tmp, nullptr,
        1024, 1024, 1024, 1024);
    ln_residual_kernel<<<2048, 256, 0, stream>>>(
        h, h_bf, tmp, ln1g + (size_t)l * DMODEL, ln1b + (size_t)l * DMODEL);
    // FFN1 (bf16 out, bias+relu)
    mgemm2<1, 1, 1><<<dim3(16, 32), 256, 0, stream>>>(
        h_bf, nullptr, 0, w1 + (size_t)l * 4194304, ffh_bf,
        ffb1 + (size_t)l * DINNER, 1024, 1024, 1024, 4096);
    // FFN2 (f32 out, bias)
    mgemm2<0, 0, 1><<<dim3(16, 8), 256, 0, stream>>>(
        ffh_bf, nullptr, 0, w2 + (size_t)l * 4194304, tmp,
        ffb2 + (size_t)l * DMODEL, 4096, 4096, 4096, 1024);
    ln_residual_kernel<<<2048, 256, 0, stream>>>(
        h, h_bf, tmp, ln2g + (size_t)l * DMODEL, ln2b + (size_t)l * DMODEL);
  }

  out_kernel<<<dim3(QLEN, BATCH), 256, 0, stream>>>(h, (float*)d_out);
}

// Round 7
// 1203.980 us; speedup vs baseline: 1.1618x; 1.1618x over previous
//
#include <hip/hip_runtime.h>
#include <cstdint>

#define NLAYER 4
#define DMODEL 1024
#define NHEAD 16
#define DHEAD 64
#define DINNER 4096
#define QLEN 512
#define MLEN 512
#define KLEN (QLEN + MLEN)
#define BATCH 4
#define ND (NHEAD * DHEAD)

typedef unsigned short u16;
typedef __attribute__((ext_vector_type(8))) short short8;
typedef __attribute__((ext_vector_type(4))) float f32x4;
typedef __attribute__((address_space(1))) const unsigned int guint;
typedef __attribute__((address_space(3))) unsigned int luint;

__device__ __forceinline__ u16 f2b(float x) {
  unsigned u = __builtin_bit_cast(unsigned, x);
  return (u16)((u + 0x7fffu + ((u >> 16) & 1u)) >> 16);
}
__device__ __forceinline__ float b2f(u16 h) {
  return __builtin_bit_cast(float, (unsigned)h << 16);
}

// ---------------- f32 -> bf16 bulk convert ----------------
__global__ __launch_bounds__(256) void conv_bf16(
    const float* __restrict__ s, u16* __restrict__ d, int n8)
{
  const int i = blockIdx.x * 256 + threadIdx.x;
  if (i >= n8) return;
  const float4 a = ((const float4*)s)[2 * i], b = ((const float4*)s)[2 * i + 1];
  union { u16 u[8]; float4 v; } p;
  p.u[0] = f2b(a.x); p.u[1] = f2b(a.y); p.u[2] = f2b(a.z); p.u[3] = f2b(a.w);
  p.u[4] = f2b(b.x); p.u[5] = f2b(b.y); p.u[6] = f2b(b.z); p.u[7] = f2b(b.w);
  ((float4*)d)[i] = p.v;
}

// ---------------- embedding gather ----------------
__global__ __launch_bounds__(256) void embed_kernel(
    const int* __restrict__ tok, const float* __restrict__ emb,
    float* __restrict__ h, u16* __restrict__ hb)
{
  const int q = blockIdx.x, b = blockIdx.y, t = threadIdx.x;
  const int id = tok[b * QLEN + q];
  const float4 v = ((const float4*)(emb + (size_t)id * DMODEL))[t];
  const size_t row = (size_t)q * BATCH + b;
  ((float4*)(h + row * DMODEL))[t] = v;
  union { u16 u[4]; float2 f; } p;
  p.u[0] = f2b(v.x); p.u[1] = f2b(v.y); p.u[2] = f2b(v.z); p.u[3] = f2b(v.w);
  *(float2*)(hb + row * DMODEL + t * 4) = p.f;
}

// ---------------- sinusoidal pos emb (bf16 out) ----------------
__global__ __launch_bounds__(256) void posemb_kernel(u16* __restrict__ pe)
{
  const int k = blockIdx.x, t = threadIdx.x;
  const float pos = (float)(KLEN - 1 - k);
  for (int i = t; i < DMODEL / 2; i += 256) {
    const float inv_freq = powf(10000.0f, -(float)(2 * i) / (float)DMODEL);
    const float a = pos * inv_freq;
    pe[(size_t)k * DMODEL + i] = f2b(sinf(a));
    pe[(size_t)k * DMODEL + DMODEL / 2 + i] = f2b(cosf(a));
  }
}

// ======== mgemm2: m97-style NT GEMM with global_load_lds + XOR swizzle ========
template<int OUTBF, int RELU, int BIAS>
__global__ __launch_bounds__(256) void mgemm2(
    const u16* __restrict__ A0, const u16* __restrict__ A1, int splitRow,
    const u16* __restrict__ B, void* __restrict__ Cp,
    const float* __restrict__ bias, int Kd, long sa, long sb, long sc)
{
  __shared__ u16 As[128][64];
  __shared__ u16 Bs[128][64];
  const int bm = blockIdx.x * 128, bn = blockIdx.y * 128;
  const int t = threadIdx.x, wave = t >> 6, lane = t & 63;
  const int wm = (wave >> 1) * 64, wn = (wave & 1) * 64;
  const int lrow = lane & 15, lk = lane >> 4;
  const int srow0 = wave * 32 + (lane >> 3);
  const int sg = lane & 7;
  const u16* arow[4];
  const u16* brow[4];
  int gsw[4];
#pragma unroll
  for (int c = 0; c < 4; ++c) {
    const int row = srow0 + c * 8;
    gsw[c] = (sg ^ (row & 7)) * 8;
    const int ga = bm + row;
    arow[c] = (A1 != nullptr && ga >= splitRow) ? (A1 + (size_t)(ga - splitRow) * sa)
                                                : (A0 + (size_t)ga * sa);
    brow[c] = B + (size_t)(bn + row) * sb;
  }
  f32x4 acc[4][4] = {};
  for (int k0 = 0; k0 < Kd; k0 += 64) {
    __syncthreads();
#pragma unroll
    for (int c = 0; c < 4; ++c) {
      __builtin_amdgcn_global_load_lds((guint*)(arow[c] + k0 + gsw[c]),
                                       (luint*)&As[wave * 32 + c * 8][0], 16, 0, 0);
      __builtin_amdgcn_global_load_lds((guint*)(brow[c] + k0 + gsw[c]),
                                       (luint*)&Bs[wave * 32 + c * 8][0], 16, 0, 0);
    }
    __syncthreads();
#pragma unroll
    for (int ks = 0; ks < 2; ++ks) {
      short8 af[4], bf[4];
#pragma unroll
      for (int x = 0; x < 4; ++x) {
        const int ra = wm + x * 16 + lrow;
        const int rb = wn + x * 16 + lrow;
        af[x] = *(const short8*)((const u16*)As + ra * 64 + (((ks * 4 + lk) ^ (ra & 7)) * 8));
        bf[x] = *(const short8*)((const u16*)Bs + rb * 64 + (((ks * 4 + lk) ^ (rb & 7)) * 8));
      }
#pragma unroll
      for (int mi = 0; mi < 4; ++mi)
#pragma unroll
        for (int ni = 0; ni < 4; ++ni)
          acc[mi][ni] = __builtin_amdgcn_mfma_f32_16x16x32_bf16(af[mi], bf[ni], acc[mi][ni], 0, 0, 0);
    }
  }
  const size_t row0 = bm + wm + lk * 4;
  const size_t col0 = bn + wn + lrow;
#pragma unroll
  for (int mi = 0; mi < 4; ++mi)
#pragma unroll
    for (int r = 0; r < 4; ++r) {
      const size_t row = row0 + mi * 16 + r;
#pragma unroll
      for (int ni = 0; ni < 4; ++ni) {
        float v = acc[mi][ni][r];
        if (BIAS) v += bias[col0 + ni * 16];
        if (RELU) v = fmaxf(v, 0.0f);
        if (OUTBF) ((u16*)Cp)[row * sc + col0 + ni * 16] = f2b(v);
        else       ((float*)Cp)[row * sc + col0 + ni * 16] = v;
      }
    }
}

// ---------------- BD GEMM with rel-shift folded into the store ----------------
// BDs[slice][i][j] = qb_i . r_s  with j = s + i - 511 (stored iff j >= 0).
__global__ __launch_bounds__(256) void bd_gemm(
    const u16* __restrict__ A, const u16* __restrict__ B, u16* __restrict__ S)
{
  __shared__ u16 As[128][40];
  __shared__ u16 Bs[128][40];
  const int z = blockIdx.z, zb = z & 3, zn = z >> 2;
  const u16* Ab = A + (size_t)zb * 524288 + zn * 64;   // qb [b][i][nd]
  const u16* Bb = B + zn * 64;                          // rb [s][nd]
  u16* Sb = S + (size_t)(zn * 4 + zb) * 524288;
  const int bm = blockIdx.x * 128, bn = blockIdx.y * 128;
  const int t = threadIdx.x, wave = t >> 6, lane = t & 63;
  const int wm = (wave >> 1) * 64, wn = (wave & 1) * 64;
  const int lrow = lane & 15, lk = lane >> 4;
  const int srow = t >> 2, skc = (t & 3) * 8;
  f32x4 acc[4][4] = {};
  for (int k0 = 0; k0 < 64; k0 += 32) {
    const float4 a0 = *(const float4*)(Ab + (size_t)(bm + srow) * 1024 + k0 + skc);
    const float4 a1 = *(const float4*)(Ab + (size_t)(bm + srow + 64) * 1024 + k0 + skc);
    const float4 b0 = *(const float4*)(Bb + (size_t)(bn + srow) * 1024 + k0 + skc);
    const float4 b1 = *(const float4*)(Bb + (size_t)(bn + srow + 64) * 1024 + k0 + skc);
    __syncthreads();
    *(float4*)&As[srow][skc] = a0; *(float4*)&As[srow + 64][skc] = a1;
    *(float4*)&Bs[srow][skc] = b0; *(float4*)&Bs[srow + 64][skc] = b1;
    __syncthreads();
    short8 af[4], bf[4];
#pragma unroll
    for (int x = 0; x < 4; ++x) af[x] = *(const short8*)&As[wm + x * 16 + lrow][lk * 8];
#pragma unroll
    for (int x = 0; x < 4; ++x) bf[x] = *(const short8*)&Bs[wn + x * 16 + lrow][lk * 8];
#pragma unroll
    for (int mi = 0; mi < 4; ++mi)
#pragma unroll
      for (int ni = 0; ni < 4; ++ni)
        acc[mi][ni] = __builtin_amdgcn_mfma_f32_16x16x32_bf16(af[mi], bf[ni], acc[mi][ni], 0, 0, 0);
  }
  const int row0 = bm + wm + lk * 4;
  const int col0 = bn + wn + lrow;
#pragma unroll
  for (int mi = 0; mi < 4; ++mi)
#pragma unroll
    for (int r = 0; r < 4; ++r) {
      const int row = row0 + mi * 16 + r;
#pragma unroll
      for (int ni = 0; ni < 4; ++ni) {
        const int j = col0 + ni * 16 + row - 511;
        if (j >= 0) Sb[(size_t)row * 1024 + j] = f2b(acc[mi][ni][r]);
      }
    }
}

// ---------------- qa/qb prep ----------------
__global__ __launch_bounds__(256) void qprep_kernel(
    const u16* __restrict__ qkvb, const float* __restrict__ rwb,
    const float* __restrict__ rrb, u16* __restrict__ qa, u16* __restrict__ qb)
{
  const int i = blockIdx.x, b = blockIdx.y, t = threadIdx.x;
  const int c = t * 4;
  const size_t src = ((size_t)(QLEN + i) * BATCH + b) * (3 * ND) + c;
  const size_t dst = ((size_t)b * QLEN + i) * ND + c;
  union { u16 u[4]; float2 f; } qi, oa, ob;
  qi.f = *(const float2*)(qkvb + src);
#pragma unroll
  for (int e = 0; e < 4; ++e) {
    const float q = b2f(qi.u[e]);
    oa.u[e] = f2b(q + rwb[c + e]);
    ob.u[e] = f2b(q + rrb[c + e]);
  }
  *(float2*)(qa + dst) = oa.f;
  *(float2*)(qb + dst) = ob.f;
}

// ---------------- V transpose: qkv V -> Vt[b][n][d][j] ----------------
__global__ __launch_bounds__(256) void vtrans_kernel(
    const u16* __restrict__ qkvb, u16* __restrict__ Vt)
{
  __shared__ u16 T[64][72];
  const int j0 = blockIdx.x * 64;
  const int bn = blockIdx.y, b = bn >> 4, n = bn & 15;
  const int t = threadIdx.x;
  const int jl = t >> 3, ch = t & 7;
#pragma unroll
  for (int p = 0; p < 2; ++p) {
    const int jj = p * 32 + jl;
    const float4 v = *(const float4*)(qkvb + ((size_t)(j0 + jj) * BATCH + b) * (3 * ND)
                                      + 2 * ND + n * 64 + ch * 8);
    *(float4*)&T[jj][ch * 8] = v;
  }
  __syncthreads();
#pragma unroll
  for (int p = 0; p < 2; ++p) {
    const int dd = p * 32 + jl;
    union { u16 u[8]; float4 v; } o;
#pragma unroll
    for (int e = 0; e < 8; ++e) o.u[e] = T[ch * 8 + e][dd];
    *(float4*)(Vt + ((size_t)(b * 16 + n) * 64 + dd) * 1024 + j0 + ch * 8) = o.v;
  }
}

// -------- flash attention: AC + pre-shifted BD + softmax + PV, pipelined --------
// double-buffered K/V LDS, 1 barrier/tile, K/V/BD prefetched one tile ahead.
__global__ __launch_bounds__(256) void flash_attn(
    const u16* __restrict__ qa, const u16* __restrict__ qkvb,
    const u16* __restrict__ Vt, const u16* __restrict__ BDs,
    u16* __restrict__ O)
{
  __shared__ u16 qs[64][72];
  __shared__ u16 ks[2][64][72];
  __shared__ u16 vs[2][64][72];
  __shared__ u16 ps[4][16][72];
  const int i0 = blockIdx.x * 64;
  const int n = blockIdx.y, b = blockIdx.z;
  const int t = threadIdx.x, wave = t >> 6, lane = t & 63;
  const int lrow = lane & 15, lk = lane >> 4;
  const int sr = t >> 2, sc = (t & 3) * 8;
  const int ilb = wave * 16 + lk * 4;
  {
    const u16* src = qa + ((size_t)b * QLEN + i0 + sr) * ND + n * 64;
    *(float4*)&qs[sr][sc] = *(const float4*)(src + sc);
    *(float4*)&qs[sr][sc + 32] = *(const float4*)(src + sc + 32);
  }
  const u16* bd = BDs + ((size_t)(n * 4 + b) * QLEN + i0) * 1024;
  const int ntiles = blockIdx.x + 9;

  float4 kr0, kr1, vr0, vr1;
  u16 bdn[16], bdc[16];
  auto LOADT = [&](int j0) {
    const u16* ksrc = qkvb + ((size_t)(j0 + sr) * BATCH + b) * (3 * ND) + ND + n * 64;
    const u16* vsrc = Vt + ((size_t)(b * 16 + n) * 64 + sr) * 1024 + j0;
    kr0 = *(const float4*)(ksrc + sc); kr1 = *(const float4*)(ksrc + sc + 32);
    vr0 = *(const float4*)(vsrc + sc); vr1 = *(const float4*)(vsrc + sc + 32);
#pragma unroll
    for (int nf = 0; nf < 4; ++nf)
#pragma unroll
      for (int r = 0; r < 4; ++r)
        bdn[nf * 4 + r] = bd[(size_t)(ilb + r) * 1024 + j0 + nf * 16 + lrow];
  };
  auto WRITET = [&](int buf) {
    *(float4*)&ks[buf][sr][sc] = kr0; *(float4*)&ks[buf][sr][sc + 32] = kr1;
    *(float4*)&vs[buf][sr][sc] = vr0; *(float4*)&vs[buf][sr][sc + 32] = vr1;
  };

  LOADT(0);
  WRITET(0);
#pragma unroll
  for (int e = 0; e < 16; ++e) bdc[e] = bdn[e];

  f32x4 o[4] = {};
  float m[4] = {-INFINITY, -INFINITY, -INFINITY, -INFINITY};
  float l[4] = {0.0f, 0.0f, 0.0f, 0.0f};

  for (int jt = 0; jt < ntiles; ++jt) {
    const int cur = jt & 1;
    const int j0 = jt * 64;
    __syncthreads();
    if (jt + 1 < ntiles) LOADT(j0 + 64);   // issued after barrier; consumed at tail
    // QK^T
    f32x4 s[4] = {};
    const short8 aq0 = *(const short8*)&qs[wave * 16 + lrow][lk * 8];
    const short8 aq1 = *(const short8*)&qs[wave * 16 + lrow][32 + lk * 8];
#pragma unroll
    for (int nf = 0; nf < 4; ++nf) {
      const short8 b0 = *(const short8*)&ks[cur][nf * 16 + lrow][lk * 8];
      const short8 b1 = *(const short8*)&ks[cur][nf * 16 + lrow][32 + lk * 8];
      s[nf] = __builtin_amdgcn_mfma_f32_16x16x32_bf16(aq0, b0, s[nf], 0, 0, 0);
      s[nf] = __builtin_amdgcn_mfma_f32_16x16x32_bf16(aq1, b1, s[nf], 0, 0, 0);
    }
    // scores: add pre-shifted BD, scale, causal mask
    float sv[4][4];
#pragma unroll
    for (int nf = 0; nf < 4; ++nf)
#pragma unroll
      for (int r = 0; r < 4; ++r) {
        const int ig = i0 + ilb + r;
        const int jg = j0 + nf * 16 + lrow;
        const float val = (s[nf][r] + b2f(bdc[nf * 4 + r])) * 0.125f;
        sv[nf][r] = (jg <= ig + MLEN) ? val : -INFINITY;
      }
    // online softmax
#pragma unroll
    for (int r = 0; r < 4; ++r) {
      float mt = fmaxf(fmaxf(sv[0][r], sv[1][r]), fmaxf(sv[2][r], sv[3][r]));
#pragma unroll
      for (int dx = 1; dx < 16; dx <<= 1) mt = fmaxf(mt, __shfl_xor(mt, dx));
      const float mnew = fmaxf(m[r], mt);
      const float alpha = __expf(m[r] - mnew);
      float ls = 0.0f;
#pragma unroll
      for (int nf = 0; nf < 4; ++nf) {
        const float pv = __expf(sv[nf][r] - mnew);
        sv[nf][r] = pv;
        ls += pv;
      }
#pragma unroll
      for (int dx = 1; dx < 16; dx <<= 1) ls += __shfl_xor(ls, dx);
      l[r] = l[r] * alpha + ls;
      m[r] = mnew;
#pragma unroll
      for (int nf = 0; nf < 4; ++nf) o[nf][r] *= alpha;
    }
    // P (C layout) -> per-wave LDS -> A-fragment layout
#pragma unroll
    for (int nf = 0; nf < 4; ++nf)
#pragma unroll
      for (int r = 0; r < 4; ++r)
        ps[wave][lk * 4 + r][nf * 16 + lrow] = f2b(sv[nf][r]);
    asm volatile("s_waitcnt lgkmcnt(0)" ::: "memory");
    __builtin_amdgcn_sched_barrier(0);
    const short8 pa0 = *(const short8*)&ps[wave][lrow][lk * 8];
    const short8 pa1 = *(const short8*)&ps[wave][lrow][32 + lk * 8];
#pragma unroll
    for (int nf = 0; nf < 4; ++nf) {
      const short8 b0 = *(const short8*)&vs[cur][nf * 16 + lrow][lk * 8];
      const short8 b1 = *(const short8*)&vs[cur][nf * 16 + lrow][32 + lk * 8];
      o[nf] = __builtin_amdgcn_mfma_f32_16x16x32_bf16(pa0, b0, o[nf], 0, 0, 0);
      o[nf] = __builtin_amdgcn_mfma_f32_16x16x32_bf16(pa1, b1, o[nf], 0, 0, 0);
    }
    if (jt + 1 < ntiles) {
      WRITET(cur ^ 1);                      // waits vmcnt for the prefetched regs
#pragma unroll
      for (int e = 0; e < 16; ++e) bdc[e] = bdn[e];
    }
  }
#pragma unroll
  for (int r = 0; r < 4; ++r) {
    const float inv = 1.0f / l[r];
    const size_t ig = i0 + ilb + r;
#pragma unroll
    for (int nf = 0; nf < 4; ++nf)
      O[(ig * BATCH + b) * ND + n * 64 + nf * 16 + lrow] = f2b(o[nf][r] * inv);
  }
}

// ---------------- fused residual + LayerNorm ----------------
__global__ __launch_bounds__(256) void ln_residual_kernel(
    float* __restrict__ h, u16* __restrict__ hb, const float* __restrict__ delta,
    const float* __restrict__ g, const float* __restrict__ bb)
{
  const int row = blockIdx.x, t = threadIdx.x;
  __shared__ float xs[DMODEL];
  __shared__ float red[256];
  float s = 0.0f;
  for (int d = t; d < DMODEL; d += 256) {
    const float v = h[(size_t)row * DMODEL + d] + delta[(size_t)row * DMODEL + d];
    xs[d] = v;
    s += v;
  }
  red[t] = s;
  __syncthreads();
  for (int w = 128; w > 0; w >>= 1) {
    if (t < w) red[t] += red[t + w];
    __syncthreads();
  }
  const float mean = red[0] * (1.0f / DMODEL);
  __syncthreads();
  float vs = 0.0f;
  for (int d = t; d < DMODEL; d += 256) {
    const float dv = xs[d] - mean;
    vs = fmaf(dv, dv, vs);
  }
  red[t] = vs;
  __syncthreads();
  for (int w = 128; w > 0; w >>= 1) {
    if (t < w) red[t] += red[t + w];
    __syncthreads();
  }
  const float rstd = rsqrtf(red[0] * (1.0f / DMODEL) + 1e-5f);
  for (int d = t; d < DMODEL; d += 256) {
    const float o = (xs[d] - mean) * rstd * g[d] + bb[d];
    h[(size_t)row * DMODEL + d] = o;
    hb[(size_t)row * DMODEL + d] = f2b(o);
  }
}

// ---------------- output transpose ----------------
__global__ __launch_bounds__(256) void out_kernel(
    const float* __restrict__ h, float* __restrict__ out)
{
  const int q = blockIdx.x, b = blockIdx.y, t = threadIdx.x;
  const float4* src = (const float4*)(h + ((size_t)q * BATCH + b) * DMODEL);
  float4* dst = (float4*)(out + ((size_t)b * QLEN + q) * DMODEL);
  dst[t] = src[t];
}

extern "C" void kernel_launch(void* const* d_in, const int* in_sizes, int n_in,
                              void* d_out, int out_size, void* d_ws, size_t ws_size,
                              hipStream_t stream)
{
  const int*   tok  = (const int*)d_in[0];
  const float* mems = (const float*)d_in[1];
  const float* wemb = (const float*)d_in[2];
  const float* qkvw = (const float*)d_in[3];
  const float* ow   = (const float*)d_in[4];
  const float* rw   = (const float*)d_in[5];
  const float* rwb  = (const float*)d_in[6];
  const float* rrb  = (const float*)d_in[7];
  const float* ln1g = (const float*)d_in[8];
  const float* ln1b = (const float*)d_in[9];
  const float* ffw1 = (const float*)d_in[10];
  const float* ffb1 = (const float*)d_in[11];
  const float* ffw2 = (const float*)d_in[12];
  const float* ffb2 = (const float*)d_in[13];
  const float* ln2g = (const float*)d_in[14];
  const float* ln2b = (const float*)d_in[15];

  float* h      = (float*)d_ws;               // [2048][1024] f32
  u16* S        = (u16*)(h + 2097152);        // BDshifted [64][512][1024] bf16 (64 MB)
  float* tmp    = (float*)S;                  // alias (BD dead after flash)
  u16* h_bf     = S + 33554432;
  u16* qkv_bf   = h_bf + 2097152;             // [4096][3072]
  u16* ffh_bf   = qkv_bf;                     // alias (qkv dead after attention)
  u16* pe_bf    = qkv_bf + 12582912;
  u16* rb_bf    = pe_bf + 1048576;
  u16* qa_bf    = rb_bf + 1048576;            // [4][512][1024]
  u16* qb_bf    = qa_bf + 2097152;
  u16* Vt       = qb_bf + 2097152;            // [4][16][64][1024]
  u16* vec_bf   = Vt + 4194304;               // [2048][1024]
  u16* mems_bf  = vec_bf + 2097152;           // [4][2048][1024]
  u16* wq = mems_bf + 8388608;                // [4][3072][1024]
  u16* wo = wq + 12582912;
  u16* wr = wo + 4194304;
  u16* w1 = wr + 4194304;                     // [4][4096][1024]
  u16* w2 = w1 + 16777216;                    // [4][1024][4096]

  embed_kernel<<<dim3(QLEN, BATCH), 256, 0, stream>>>(tok, wemb, h, h_bf);
  posemb_kernel<<<KLEN, 256, 0, stream>>>(pe_bf);

#define CONV(src, dst, n) conv_bf16<<<(n) / 2048, 256, 0, stream>>>(src, dst, (n) / 8)
  CONV(mems, mems_bf, 8388608);
  CONV(qkvw, wq, 12582912);
  CONV(ow,   wo, 4194304);
  CONV(rw,   wr, 4194304);
  CONV(ffw1, w1, 16777216);
  CONV(ffw2, w2, 16777216);

  for (int l = 0; l < NLAYER; ++l) {
    // qkv = cat(mems_bf[l], h_bf) @ qkv_w^T  (bf16 out)
    mgemm2<1, 0, 0><<<dim3(32, 24), 256, 0, stream>>>(
        mems_bf + (size_t)l * 2097152, h_bf, 2048,
        wq + (size_t)l * 3145728, qkv_bf, nullptr, 1024, 1024, 1024, 3072);
    // r = pe @ r_w^T  (bf16 out)
    mgemm2<1, 0, 0><<<dim3(8, 8), 256, 0, stream>>>(
        pe_bf, nullptr, 0, wr + (size_t)l * 1048576, rb_bf, nullptr,
        1024, 1024, 1024, 1024);

    qprep_kernel<<<dim3(QLEN, BATCH), 256, 0, stream>>>(
        qkv_bf, rwb + (size_t)l * ND, rrb + (size_t)l * ND, qa_bf, qb_bf);
    vtrans_kernel<<<dim3(16, 64), 256, 0, stream>>>(qkv_bf, Vt);

    // BDshifted[n*4+b][i][j] = qb_i . r_{j-i+511}
    bd_gemm<<<dim3(4, 8, 64), 256, 0, stream>>>(qb_bf, rb_bf, S);

    flash_attn<<<dim3(8, 16, 4), 256, 0, stream>>>(qa_bf, qkv_bf, Vt, S, vec_bf);

    // o-proj (f32 out into tmp)
    mgemm2<0, 0, 0><<<dim3(16, 8), 256, 0, stream>>>(
        vec_bf, nullptr, 0, wo + (size_t)l * 1048576, tmp, nullptr,
        1024, 1024, 1024, 1024);
    ln_residual_kernel<<<2048, 256, 0, stream>>>(
        h, h_bf, tmp, ln1g + (size_t)l * DMODEL, ln1b + (size_t)l * DMODEL);
    // FFN1 (bf16 out, bias+relu)
    mgemm2<1, 1, 1><<<dim3(16, 32), 256, 0, stream>>>(
        h_bf, nullptr, 0, w1 + (size_t)l * 4194304, ffh_bf,
        ffb1 + (size_t)l * DINNER, 1024, 1024, 1024, 4096);
    // FFN2 (f32 out, bias)
    mgemm2<0, 0, 1><<<dim3(16, 8), 256, 0, stream>>>(
        ffh_bf, nullptr, 0, w2 + (size_t)l * 4194304, tmp,
        ffb2 + (size_t)l * DMODEL, 4096, 4096, 4096, 1024);
    ln_residual_kernel<<<2048, 256, 0, stream>>>(
        h, h_bf, tmp, ln2g + (size_t)l * DMODEL, ln2b + (size_t)l * DMODEL);
  }

  out_kernel<<<dim3(QLEN, BATCH), 256, 0, stream>>>(h, (float*)d_out);
}

// Round 8
// 1061.518 us; speedup vs baseline: 1.3177x; 1.1342x over previous
//
#include <hip/hip_runtime.h>
#include <cstdint>

#define NLAYER 4
#define DMODEL 1024
#define NHEAD 16
#define DHEAD 64
#define DINNER 4096
#define QLEN 512
#define MLEN 512
#define KLEN (QLEN + MLEN)
#define BATCH 4
#define ND (NHEAD * DHEAD)

typedef unsigned short u16;
typedef __attribute__((ext_vector_type(8))) short short8;
typedef __attribute__((ext_vector_type(4))) float f32x4;
typedef __attribute__((address_space(1))) const unsigned int guint;
typedef __attribute__((address_space(3))) unsigned int luint;

__device__ __forceinline__ u16 f2b(float x) {
  unsigned u = __builtin_bit_cast(unsigned, x);
  return (u16)((u + 0x7fffu + ((u >> 16) & 1u)) >> 16);
}
__device__ __forceinline__ float b2f(u16 h) {
  return __builtin_bit_cast(float, (unsigned)h << 16);
}

// ---------------- f32 -> bf16 bulk convert ----------------
__global__ __launch_bounds__(256) void conv_bf16(
    const float* __restrict__ s, u16* __restrict__ d, int n8)
{
  const int i = blockIdx.x * 256 + threadIdx.x;
  if (i >= n8) return;
  const float4 a = ((const float4*)s)[2 * i], b = ((const float4*)s)[2 * i + 1];
  union { u16 u[8]; float4 v; } p;
  p.u[0] = f2b(a.x); p.u[1] = f2b(a.y); p.u[2] = f2b(a.z); p.u[3] = f2b(a.w);
  p.u[4] = f2b(b.x); p.u[5] = f2b(b.y); p.u[6] = f2b(b.z); p.u[7] = f2b(b.w);
  ((float4*)d)[i] = p.v;
}

// ---------------- embedding gather ----------------
__global__ __launch_bounds__(256) void embed_kernel(
    const int* __restrict__ tok, const float* __restrict__ emb,
    float* __restrict__ h, u16* __restrict__ hb)
{
  const int q = blockIdx.x, b = blockIdx.y, t = threadIdx.x;
  const int id = tok[b * QLEN + q];
  const float4 v = ((const float4*)(emb + (size_t)id * DMODEL))[t];
  const size_t row = (size_t)q * BATCH + b;
  ((float4*)(h + row * DMODEL))[t] = v;
  union { u16 u[4]; float2 f; } p;
  p.u[0] = f2b(v.x); p.u[1] = f2b(v.y); p.u[2] = f2b(v.z); p.u[3] = f2b(v.w);
  *(float2*)(hb + row * DMODEL + t * 4) = p.f;
}

// ---------------- sinusoidal pos emb (bf16 out) ----------------
__global__ __launch_bounds__(256) void posemb_kernel(u16* __restrict__ pe)
{
  const int k = blockIdx.x, t = threadIdx.x;
  const float pos = (float)(KLEN - 1 - k);
  for (int i = t; i < DMODEL / 2; i += 256) {
    const float inv_freq = powf(10000.0f, -(float)(2 * i) / (float)DMODEL);
    const float a = pos * inv_freq;
    pe[(size_t)k * DMODEL + i] = f2b(sinf(a));
    pe[(size_t)k * DMODEL + DMODEL / 2 + i] = f2b(cosf(a));
  }
}

// ======== mgemm3: 2-phase double-buffered NT GEMM, global_load_lds + XOR swizzle,
//          XCD-contiguous block remap. BM = MF*32, BN = 128, BK = 64. ========
template<int MF, int OUTBF, int RELU, int BIAS>
__global__ __launch_bounds__(256) void mgemm3(
    const u16* __restrict__ A0, const u16* __restrict__ A1, int splitRow,
    const u16* __restrict__ B, void* __restrict__ Cp,
    const float* __restrict__ bias, int Kd, long sa, long sb, long sc)
{
  constexpr int BM = MF * 32;
  constexpr int NGA = BM / 8;       // 8-row staging groups in A
  constexpr int GPW = (NGA + 16) / 4;
  __shared__ u16 As[2][BM][64];
  __shared__ u16 Bs[2][128][64];
  // XCD-contiguous remap (requires gridDim.x*gridDim.y % 8 == 0)
  const int nwg = gridDim.x * gridDim.y;
  int wg = blockIdx.y * gridDim.x + blockIdx.x;
  wg = (wg & 7) * (nwg >> 3) + (wg >> 3);
  const int bm = (wg % gridDim.x) * BM;
  const int bn = (wg / gridDim.x) * 128;
  const int t = threadIdx.x, wave = t >> 6, lane = t & 63;
  const int wm = (wave >> 1) * (MF * 16), wn = (wave & 1) * 64;
  const int lrow = lane & 15, lk = lane >> 4;
  const int gsw = ((lane & 7) ^ (lane >> 3)) * 8;  // pre-swizzled source chunk
  const u16* gptr[GPW];
  int row8[GPW];
  bool isA[GPW];
#pragma unroll
  for (int c = 0; c < GPW; ++c) {
    const int g = wave * GPW + c;
    isA[c] = g < NGA;
    row8[c] = (isA[c] ? g : g - NGA) * 8;
    const int row = row8[c] + (lane >> 3);
    if (isA[c]) {
      const int ga = bm + row;
      gptr[c] = ((A1 != nullptr && ga >= splitRow)
                     ? A1 + (size_t)(ga - splitRow) * sa
                     : A0 + (size_t)ga * sa) + gsw;
    } else {
      gptr[c] = B + (size_t)(bn + row) * sb + gsw;
    }
  }
  auto STAGE = [&](int buf, int k0) {
#pragma unroll
    for (int c = 0; c < GPW; ++c) {
      luint* dst = isA[c] ? (luint*)&As[buf][row8[c]][0] : (luint*)&Bs[buf][row8[c]][0];
      __builtin_amdgcn_global_load_lds((guint*)(gptr[c] + k0), dst, 16, 0, 0);
    }
  };
  f32x4 acc[MF][4] = {};
  const int nt = Kd >> 6;
  STAGE(0, 0);
  __syncthreads();
  for (int ti = 0; ti < nt; ++ti) {
    const int cur = ti & 1;
    if (ti + 1 < nt) STAGE(cur ^ 1, (ti + 1) << 6);  // in flight across compute
#pragma unroll
    for (int ks = 0; ks < 2; ++ks) {
      short8 af[MF], bf[4];
#pragma unroll
      for (int x = 0; x < MF; ++x) {
        const int ra = wm + x * 16 + lrow;
        af[x] = *(const short8*)((const u16*)&As[cur][0][0] + ra * 64 + (((ks * 4 + lk) ^ (ra & 7)) * 8));
      }
#pragma unroll
      for (int x = 0; x < 4; ++x) {
        const int rb = wn + x * 16 + lrow;
        bf[x] = *(const short8*)((const u16*)&Bs[cur][0][0] + rb * 64 + (((ks * 4 + lk) ^ (rb & 7)) * 8));
      }
#pragma unroll
      for (int mi = 0; mi < MF; ++mi)
#pragma unroll
        for (int ni = 0; ni < 4; ++ni)
          acc[mi][ni] = __builtin_amdgcn_mfma_f32_16x16x32_bf16(af[mi], bf[ni], acc[mi][ni], 0, 0, 0);
    }
    __syncthreads();  // drains vmcnt(0): next tile staged; LDS reads done
  }
  const size_t row0 = bm + wm + lk * 4;
  const size_t col0 = bn + wn + lrow;
#pragma unroll
  for (int mi = 0; mi < MF; ++mi)
#pragma unroll
    for (int r = 0; r < 4; ++r) {
      const size_t row = row0 + mi * 16 + r;
#pragma unroll
      for (int ni = 0; ni < 4; ++ni) {
        float v = acc[mi][ni][r];
        if (BIAS) v += bias[col0 + ni * 16];
        if (RELU) v = fmaxf(v, 0.0f);
        if (OUTBF) ((u16*)Cp)[row * sc + col0 + ni * 16] = f2b(v);
        else       ((float*)Cp)[row * sc + col0 + ni * 16] = v;
      }
    }
}

// ---------------- BD GEMM with rel-shift folded into the store ----------------
// BDs[slice][i][j] = qb_i . r_s  with j = s + i - 511 (stored iff j >= 0).
__global__ __launch_bounds__(256) void bd_gemm(
    const u16* __restrict__ A, const u16* __restrict__ B, u16* __restrict__ S)
{
  __shared__ u16 As[128][40];
  __shared__ u16 Bs[128][40];
  const int z = blockIdx.z, zb = z & 3, zn = z >> 2;
  const u16* Ab = A + (size_t)zb * 524288 + zn * 64;   // qb [b][i][nd]
  const u16* Bb = B + zn * 64;                          // rb [s][nd]
  u16* Sb = S + (size_t)(zn * 4 + zb) * 524288;
  const int bm = blockIdx.x * 128, bn = blockIdx.y * 128;
  const int t = threadIdx.x, wave = t >> 6, lane = t & 63;
  const int wm = (wave >> 1) * 64, wn = (wave & 1) * 64;
  const int lrow = lane & 15, lk = lane >> 4;
  const int srow = t >> 2, skc = (t & 3) * 8;
  f32x4 acc[4][4] = {};
  for (int k0 = 0; k0 < 64; k0 += 32) {
    const float4 a0 = *(const float4*)(Ab + (size_t)(bm + srow) * 1024 + k0 + skc);
    const float4 a1 = *(const float4*)(Ab + (size_t)(bm + srow + 64) * 1024 + k0 + skc);
    const float4 b0 = *(const float4*)(Bb + (size_t)(bn + srow) * 1024 + k0 + skc);
    const float4 b1 = *(const float4*)(Bb + (size_t)(bn + srow + 64) * 1024 + k0 + skc);
    __syncthreads();
    *(float4*)&As[srow][skc] = a0; *(float4*)&As[srow + 64][skc] = a1;
    *(float4*)&Bs[srow][skc] = b0; *(float4*)&Bs[srow + 64][skc] = b1;
    __syncthreads();
    short8 af[4], bf[4];
#pragma unroll
    for (int x = 0; x < 4; ++x) af[x] = *(const short8*)&As[wm + x * 16 + lrow][lk * 8];
#pragma unroll
    for (int x = 0; x < 4; ++x) bf[x] = *(const short8*)&Bs[wn + x * 16 + lrow][lk * 8];
#pragma unroll
    for (int mi = 0; mi < 4; ++mi)
#pragma unroll
      for (int ni = 0; ni < 4; ++ni)
        acc[mi][ni] = __builtin_amdgcn_mfma_f32_16x16x32_bf16(af[mi], bf[ni], acc[mi][ni], 0, 0, 0);
  }
  const int row0 = bm + wm + lk * 4;
  const int col0 = bn + wn + lrow;
#pragma unroll
  for (int mi = 0; mi < 4; ++mi)
#pragma unroll
    for (int r = 0; r < 4; ++r) {
      const int row = row0 + mi * 16 + r;
#pragma unroll
      for (int ni = 0; ni < 4; ++ni) {
        const int j = col0 + ni * 16 + row - 511;
        if (j >= 0) Sb[(size_t)row * 1024 + j] = f2b(acc[mi][ni][r]);
      }
    }
}

// ---------------- qa/qb prep ----------------
__global__ __launch_bounds__(256) void qprep_kernel(
    const u16* __restrict__ qkvb, const float* __restrict__ rwb,
    const float* __restrict__ rrb, u16* __restrict__ qa, u16* __restrict__ qb)
{
  const int i = blockIdx.x, b = blockIdx.y, t = threadIdx.x;
  const int c = t * 4;
  const size_t src = ((size_t)(QLEN + i) * BATCH + b) * (3 * ND) + c;
  const size_t dst = ((size_t)b * QLEN + i) * ND + c;
  union { u16 u[4]; float2 f; } qi, oa, ob;
  qi.f = *(const float2*)(qkvb + src);
#pragma unroll
  for (int e = 0; e < 4; ++e) {
    const float q = b2f(qi.u[e]);
    oa.u[e] = f2b(q + rwb[c + e]);
    ob.u[e] = f2b(q + rrb[c + e]);
  }
  *(float2*)(qa + dst) = oa.f;
  *(float2*)(qb + dst) = ob.f;
}

// ---------------- V transpose: qkv V -> Vt[b][n][d][j] ----------------
__global__ __launch_bounds__(256) void vtrans_kernel(
    const u16* __restrict__ qkvb, u16* __restrict__ Vt)
{
  __shared__ u16 T[64][72];
  const int j0 = blockIdx.x * 64;
  const int bn = blockIdx.y, b = bn >> 4, n = bn & 15;
  const int t = threadIdx.x;
  const int jl = t >> 3, ch = t & 7;
#pragma unroll
  for (int p = 0; p < 2; ++p) {
    const int jj = p * 32 + jl;
    const float4 v = *(const float4*)(qkvb + ((size_t)(j0 + jj) * BATCH + b) * (3 * ND)
                                      + 2 * ND + n * 64 + ch * 8);
    *(float4*)&T[jj][ch * 8] = v;
  }
  __syncthreads();
#pragma unroll
  for (int p = 0; p < 2; ++p) {
    const int dd = p * 32 + jl;
    union { u16 u[8]; float4 v; } o;
#pragma unroll
    for (int e = 0; e < 8; ++e) o.u[e] = T[ch * 8 + e][dd];
    *(float4*)(Vt + ((size_t)(b * 16 + n) * 64 + dd) * 1024 + j0 + ch * 8) = o.v;
  }
}

// -------- flash attention: AC + pre-shifted BD + softmax + PV, pipelined --------
__global__ __launch_bounds__(256) void flash_attn(
    const u16* __restrict__ qa, const u16* __restrict__ qkvb,
    const u16* __restrict__ Vt, const u16* __restrict__ BDs,
    u16* __restrict__ O)
{
  __shared__ u16 qs[64][72];
  __shared__ u16 ks[2][64][72];
  __shared__ u16 vs[2][64][72];
  __shared__ u16 ps[4][16][72];
  const int i0 = blockIdx.x * 64;
  const int n = blockIdx.y, b = blockIdx.z;
  const int t = threadIdx.x, wave = t >> 6, lane = t & 63;
  const int lrow = lane & 15, lk = lane >> 4;
  const int sr = t >> 2, sc = (t & 3) * 8;
  const int ilb = wave * 16 + lk * 4;
  {
    const u16* src = qa + ((size_t)b * QLEN + i0 + sr) * ND + n * 64;
    *(float4*)&qs[sr][sc] = *(const float4*)(src + sc);
    *(float4*)&qs[sr][sc + 32] = *(const float4*)(src + sc + 32);
  }
  const u16* bd = BDs + ((size_t)(n * 4 + b) * QLEN + i0) * 1024;
  const int ntiles = blockIdx.x + 9;

  float4 kr0, kr1, vr0, vr1;
  u16 bdn[16], bdc[16];
  auto LOADT = [&](int j0) {
    const u16* ksrc = qkvb + ((size_t)(j0 + sr) * BATCH + b) * (3 * ND) + ND + n * 64;
    const u16* vsrc = Vt + ((size_t)(b * 16 + n) * 64 + sr) * 1024 + j0;
    kr0 = *(const float4*)(ksrc + sc); kr1 = *(const float4*)(ksrc + sc + 32);
    vr0 = *(const float4*)(vsrc + sc); vr1 = *(const float4*)(vsrc + sc + 32);
#pragma unroll
    for (int nf = 0; nf < 4; ++nf)
#pragma unroll
      for (int r = 0; r < 4; ++r)
        bdn[nf * 4 + r] = bd[(size_t)(ilb + r) * 1024 + j0 + nf * 16 + lrow];
  };
  auto WRITET = [&](int buf) {
    *(float4*)&ks[buf][sr][sc] = kr0; *(float4*)&ks[buf][sr][sc + 32] = kr1;
    *(float4*)&vs[buf][sr][sc] = vr0; *(float4*)&vs[buf][sr][sc + 32] = vr1;
  };

  LOADT(0);
  WRITET(0);
#pragma unroll
  for (int e = 0; e < 16; ++e) bdc[e] = bdn[e];

  f32x4 o[4] = {};
  float m[4] = {-INFINITY, -INFINITY, -INFINITY, -INFINITY};
  float l[4] = {0.0f, 0.0f, 0.0f, 0.0f};

  for (int jt = 0; jt < ntiles; ++jt) {
    const int cur = jt & 1;
    const int j0 = jt * 64;
    __syncthreads();
    if (jt + 1 < ntiles) LOADT(j0 + 64);
    f32x4 s[4] = {};
    const short8 aq0 = *(const short8*)&qs[wave * 16 + lrow][lk * 8];
    const short8 aq1 = *(const short8*)&qs[wave * 16 + lrow][32 + lk * 8];
#pragma unroll
    for (int nf = 0; nf < 4; ++nf) {
      const short8 b0 = *(const short8*)&ks[cur][nf * 16 + lrow][lk * 8];
      const short8 b1 = *(const short8*)&ks[cur][nf * 16 + lrow][32 + lk * 8];
      s[nf] = __builtin_amdgcn_mfma_f32_16x16x32_bf16(aq0, b0, s[nf], 0, 0, 0);
      s[nf] = __builtin_amdgcn_mfma_f32_16x16x32_bf16(aq1, b1, s[nf], 0, 0, 0);
    }
    float sv[4][4];
#pragma unroll
    for (int nf = 0; nf < 4; ++nf)
#pragma unroll
      for (int r = 0; r < 4; ++r) {
        const int ig = i0 + ilb + r;
        const int jg = j0 + nf * 16 + lrow;
        const float val = (s[nf][r] + b2f(bdc[nf * 4 + r])) * 0.125f;
        sv[nf][r] = (jg <= ig + MLEN) ? val : -INFINITY;
      }
#pragma unroll
    for (int r = 0; r < 4; ++r) {
      float mt = fmaxf(fmaxf(sv[0][r], sv[1][r]), fmaxf(sv[2][r], sv[3][r]));
#pragma unroll
      for (int dx = 1; dx < 16; dx <<= 1) mt = fmaxf(mt, __shfl_xor(mt, dx));
      const float mnew = fmaxf(m[r], mt);
      const float alpha = __expf(m[r] - mnew);
      float ls = 0.0f;
#pragma unroll
      for (int nf = 0; nf < 4; ++nf) {
        const float pv = __expf(sv[nf][r] - mnew);
        sv[nf][r] = pv;
        ls += pv;
      }
#pragma unroll
      for (int dx = 1; dx < 16; dx <<= 1) ls += __shfl_xor(ls, dx);
      l[r] = l[r] * alpha + ls;
      m[r] = mnew;
#pragma unroll
      for (int nf = 0; nf < 4; ++nf) o[nf][r] *= alpha;
    }
#pragma unroll
    for (int nf = 0; nf < 4; ++nf)
#pragma unroll
      for (int r = 0; r < 4; ++r)
        ps[wave][lk * 4 + r][nf * 16 + lrow] = f2b(sv[nf][r]);
    asm volatile("s_waitcnt lgkmcnt(0)" ::: "memory");
    __builtin_amdgcn_sched_barrier(0);
    const short8 pa0 = *(const short8*)&ps[wave][lrow][lk * 8];
    const short8 pa1 = *(const short8*)&ps[wave][lrow][32 + lk * 8];
#pragma unroll
    for (int nf = 0; nf < 4; ++nf) {
      const short8 b0 = *(const short8*)&vs[cur][nf * 16 + lrow][lk * 8];
      const short8 b1 = *(const short8*)&vs[cur][nf * 16 + lrow][32 + lk * 8];
      o[nf] = __builtin_amdgcn_mfma_f32_16x16x32_bf16(pa0, b0, o[nf], 0, 0, 0);
      o[nf] = __builtin_amdgcn_mfma_f32_16x16x32_bf16(pa1, b1, o[nf], 0, 0, 0);
    }
    if (jt + 1 < ntiles) {
      WRITET(cur ^ 1);
#pragma unroll
      for (int e = 0; e < 16; ++e) bdc[e] = bdn[e];
    }
  }
#pragma unroll
  for (int r = 0; r < 4; ++r) {
    const float inv = 1.0f / l[r];
    const size_t ig = i0 + ilb + r;
#pragma unroll
    for (int nf = 0; nf < 4; ++nf)
      O[(ig * BATCH + b) * ND + n * 64 + nf * 16 + lrow] = f2b(o[nf][r] * inv);
  }
}

// ---------------- fused residual + LayerNorm ----------------
__global__ __launch_bounds__(256) void ln_residual_kernel(
    float* __restrict__ h, u16* __restrict__ hb, const float* __restrict__ delta,
    const float* __restrict__ g, const float* __restrict__ bb)
{
  const int row = blockIdx.x, t = threadIdx.x;
  __shared__ float xs[DMODEL];
  __shared__ float red[256];
  float s = 0.0f;
  for (int d = t; d < DMODEL; d += 256) {
    const float v = h[(size_t)row * DMODEL + d] + delta[(size_t)row * DMODEL + d];
    xs[d] = v;
    s += v;
  }
  red[t] = s;
  __syncthreads();
  for (int w = 128; w > 0; w >>= 1) {
    if (t < w) red[t] += red[t + w];
    __syncthreads();
  }
  const float mean = red[0] * (1.0f / DMODEL);
  __syncthreads();
  float vs = 0.0f;
  for (int d = t; d < DMODEL; d += 256) {
    const float dv = xs[d] - mean;
    vs = fmaf(dv, dv, vs);
  }
  red[t] = vs;
  __syncthreads();
  for (int w = 128; w > 0; w >>= 1) {
    if (t < w) red[t] += red[t + w];
    __syncthreads();
  }
  const float rstd = rsqrtf(red[0] * (1.0f / DMODEL) + 1e-5f);
  for (int d = t; d < DMODEL; d += 256) {
    const float o = (xs[d] - mean) * rstd * g[d] + bb[d];
    h[(size_t)row * DMODEL + d] = o;
    hb[(size_t)row * DMODEL + d] = f2b(o);
  }
}

// ---------------- output transpose ----------------
__global__ __launch_bounds__(256) void out_kernel(
    const float* __restrict__ h, float* __restrict__ out)
{
  const int q = blockIdx.x, b = blockIdx.y, t = threadIdx.x;
  const float4* src = (const float4*)(h + ((size_t)q * BATCH + b) * DMODEL);
  float4* dst = (float4*)(out + ((size_t)b * QLEN + q) * DMODEL);
  dst[t] = src[t];
}

extern "C" void kernel_launch(void* const* d_in, const int* in_sizes, int n_in,
                              void* d_out, int out_size, void* d_ws, size_t ws_size,
                              hipStream_t stream)
{
  const int*   tok  = (const int*)d_in[0];
  const float* mems = (const float*)d_in[1];
  const float* wemb = (const float*)d_in[2];
  const float* qkvw = (const float*)d_in[3];
  const float* ow   = (const float*)d_in[4];
  const float* rw   = (const float*)d_in[5];
  const float* rwb  = (const float*)d_in[6];
  const float* rrb  = (const float*)d_in[7];
  const float* ln1g = (const float*)d_in[8];
  const float* ln1b = (const float*)d_in[9];
  const float* ffw1 = (const float*)d_in[10];
  const float* ffb1 = (const float*)d_in[11];
  const float* ffw2 = (const float*)d_in[12];
  const float* ffb2 = (const float*)d_in[13];
  const float* ln2g = (const float*)d_in[14];
  const float* ln2b = (const float*)d_in[15];

  float* h      = (float*)d_ws;               // [2048][1024] f32
  u16* S        = (u16*)(h + 2097152);        // BDshifted [64][512][1024] bf16 (64 MB)
  float* tmp    = (float*)S;                  // alias (BD dead after flash)
  u16* h_bf     = S + 33554432;
  u16* qkv_bf   = h_bf + 2097152;             // [4096][3072]
  u16* ffh_bf   = qkv_bf;                     // alias (qkv dead after attention)
  u16* pe_bf    = qkv_bf + 12582912;
  u16* rb_bf    = pe_bf + 1048576;
  u16* qa_bf    = rb_bf + 1048576;            // [4][512][1024]
  u16* qb_bf    = qa_bf + 2097152;
  u16* Vt       = qb_bf + 2097152;            // [4][16][64][1024]
  u16* vec_bf   = Vt + 4194304;               // [2048][1024]
  u16* mems_bf  = vec_bf + 2097152;           // [4][2048][1024]
  u16* wq = mems_bf + 8388608;                // [4][3072][1024]
  u16* wo = wq + 12582912;
  u16* wr = wo + 4194304;
  u16* w1 = wr + 4194304;                     // [4][4096][1024]
  u16* w2 = w1 + 16777216;                    // [4][1024][4096]

  embed_kernel<<<dim3(QLEN, BATCH), 256, 0, stream>>>(tok, wemb, h, h_bf);
  posemb_kernel<<<KLEN, 256, 0, stream>>>(pe_bf);

#define CONV(src, dst, n) conv_bf16<<<(n) / 2048, 256, 0, stream>>>(src, dst, (n) / 8)
  CONV(mems, mems_bf, 8388608);
  CONV(qkvw, wq, 12582912);
  CONV(ow,   wo, 4194304);
  CONV(rw,   wr, 4194304);
  CONV(ffw1, w1, 16777216);
  CONV(ffw2, w2, 16777216);

  for (int l = 0; l < NLAYER; ++l) {
    // qkv = cat(mems_bf[l], h_bf) @ qkv_w^T  (bf16 out)
    mgemm3<4, 1, 0, 0><<<dim3(32, 24), 256, 0, stream>>>(
        mems_bf + (size_t)l * 2097152, h_bf, 2048,
        wq + (size_t)l * 3145728, qkv_bf, nullptr, 1024, 1024, 1024, 3072);
    // r = pe @ r_w^T  (bf16 out)
    mgemm3<2, 1, 0, 0><<<dim3(16, 8), 256, 0, stream>>>(
        pe_bf, nullptr, 0, wr + (size_t)l * 1048576, rb_bf, nullptr,
        1024, 1024, 1024, 1024);

    qprep_kernel<<<dim3(QLEN, BATCH), 256, 0, stream>>>(
        qkv_bf, rwb + (size_t)l * ND, rrb + (size_t)l * ND, qa_bf, qb_bf);
    vtrans_kernel<<<dim3(16, 64), 256, 0, stream>>>(qkv_bf, Vt);

    // BDshifted[n*4+b][i][j] = qb_i . r_{j-i+511}
    bd_gemm<<<dim3(4, 8, 64), 256, 0, stream>>>(qb_bf, rb_bf, S);

    flash_attn<<<dim3(8, 16, 4), 256, 0, stream>>>(qa_bf, qkv_bf, Vt, S, vec_bf);

    // o-proj (f32 out into tmp)
    mgemm3<2, 0, 0, 0><<<dim3(32, 8), 256, 0, stream>>>(
        vec_bf, nullptr, 0, wo + (size_t)l * 1048576, tmp, nullptr,
        1024, 1024, 1024, 1024);
    ln_residual_kernel<<<2048, 256, 0, stream>>>(
        h, h_bf, tmp, ln1g + (size_t)l * DMODEL, ln1b + (size_t)l * DMODEL);
    // FFN1 (bf16 out, bias+relu)
    mgemm3<4, 1, 1, 1><<<dim3(16, 32), 256, 0, stream>>>(
        h_bf, nullptr, 0, w1 + (size_t)l * 4194304, ffh_bf,
        ffb1 + (size_t)l * DINNER, 1024, 1024, 1024, 4096);
    // FFN2 (f32 out, bias)
    mgemm3<2, 0, 0, 1><<<dim3(32, 8), 256, 0, stream>>>(
        ffh_bf, nullptr, 0, w2 + (size_t)l * 4194304, tmp,
        ffb2 + (size_t)l * DMODEL, 4096, 4096, 4096, 1024);
    ln_residual_kernel<<<2048, 256, 0, stream>>>(
        h, h_bf, tmp, ln2g + (size_t)l * DMODEL, ln2b + (size_t)l * DMODEL);
  }

  out_kernel<<<dim3(QLEN, BATCH), 256, 0, stream>>>(h, (float*)d_out);
}

// Round 9
// 1023.959 us; speedup vs baseline: 1.3660x; 1.0367x over previous
//
#include <hip/hip_runtime.h>
#include <cstdint>

#define NLAYER 4
#define DMODEL 1024
#define NHEAD 16
#define DHEAD 64
#define DINNER 4096
#define QLEN 512
#define MLEN 512
#define KLEN (QLEN + MLEN)
#define BATCH 4
#define ND (NHEAD * DHEAD)

typedef unsigned short u16;
typedef __attribute__((ext_vector_type(8))) short short8;
typedef __attribute__((ext_vector_type(4))) float f32x4;
typedef __attribute__((address_space(1))) const unsigned int guint;
typedef __attribute__((address_space(3))) unsigned int luint;

__device__ __forceinline__ u16 f2b(float x) {
  unsigned u = __builtin_bit_cast(unsigned, x);
  return (u16)((u + 0x7fffu + ((u >> 16) & 1u)) >> 16);
}
__device__ __forceinline__ float b2f(u16 h) {
  return __builtin_bit_cast(float, (unsigned)h << 16);
}

// ---------------- f32 -> bf16 bulk convert ----------------
__global__ __launch_bounds__(256) void conv_bf16(
    const float* __restrict__ s, u16* __restrict__ d, int n8)
{
  const int i = blockIdx.x * 256 + threadIdx.x;
  if (i >= n8) return;
  const float4 a = ((const float4*)s)[2 * i], b = ((const float4*)s)[2 * i + 1];
  union { u16 u[8]; float4 v; } p;
  p.u[0] = f2b(a.x); p.u[1] = f2b(a.y); p.u[2] = f2b(a.z); p.u[3] = f2b(a.w);
  p.u[4] = f2b(b.x); p.u[5] = f2b(b.y); p.u[6] = f2b(b.z); p.u[7] = f2b(b.w);
  ((float4*)d)[i] = p.v;
}

// ---------------- embedding gather ----------------
__global__ __launch_bounds__(256) void embed_kernel(
    const int* __restrict__ tok, const float* __restrict__ emb,
    float* __restrict__ h, u16* __restrict__ hb)
{
  const int q = blockIdx.x, b = blockIdx.y, t = threadIdx.x;
  const int id = tok[b * QLEN + q];
  const float4 v = ((const float4*)(emb + (size_t)id * DMODEL))[t];
  const size_t row = (size_t)q * BATCH + b;
  ((float4*)(h + row * DMODEL))[t] = v;
  union { u16 u[4]; float2 f; } p;
  p.u[0] = f2b(v.x); p.u[1] = f2b(v.y); p.u[2] = f2b(v.z); p.u[3] = f2b(v.w);
  *(float2*)(hb + row * DMODEL + t * 4) = p.f;
}

// ---------------- sinusoidal pos emb (bf16 out) ----------------
__global__ __launch_bounds__(256) void posemb_kernel(u16* __restrict__ pe)
{
  const int k = blockIdx.x, t = threadIdx.x;
  const float pos = (float)(KLEN - 1 - k);
  for (int i = t; i < DMODEL / 2; i += 256) {
    const float inv_freq = powf(10000.0f, -(float)(2 * i) / (float)DMODEL);
    const float a = pos * inv_freq;
    pe[(size_t)k * DMODEL + i] = f2b(sinf(a));
    pe[(size_t)k * DMODEL + DMODEL / 2 + i] = f2b(cosf(a));
  }
}

// ======== mgemm3: 2-phase double-buffered NT GEMM (unchanged, validated) ========
template<int MF, int OUTBF, int RELU, int BIAS>
__global__ __launch_bounds__(256) void mgemm3(
    const u16* __restrict__ A0, const u16* __restrict__ A1, int splitRow,
    const u16* __restrict__ B, void* __restrict__ Cp,
    const float* __restrict__ bias, int Kd, long sa, long sb, long sc)
{
  constexpr int BM = MF * 32;
  constexpr int NGA = BM / 8;
  constexpr int GPW = (NGA + 16) / 4;
  __shared__ u16 As[2][BM][64];
  __shared__ u16 Bs[2][128][64];
  const int nwg = gridDim.x * gridDim.y;
  int wg = blockIdx.y * gridDim.x + blockIdx.x;
  wg = (wg & 7) * (nwg >> 3) + (wg >> 3);
  const int bm = (wg % gridDim.x) * BM;
  const int bn = (wg / gridDim.x) * 128;
  const int t = threadIdx.x, wave = t >> 6, lane = t & 63;
  const int wm = (wave >> 1) * (MF * 16), wn = (wave & 1) * 64;
  const int lrow = lane & 15, lk = lane >> 4;
  const int gsw = ((lane & 7) ^ (lane >> 3)) * 8;
  const u16* gptr[GPW];
  int row8[GPW];
  bool isA[GPW];
#pragma unroll
  for (int c = 0; c < GPW; ++c) {
    const int g = wave * GPW + c;
    isA[c] = g < NGA;
    row8[c] = (isA[c] ? g : g - NGA) * 8;
    const int row = row8[c] + (lane >> 3);
    if (isA[c]) {
      const int ga = bm + row;
      gptr[c] = ((A1 != nullptr && ga >= splitRow)
                     ? A1 + (size_t)(ga - splitRow) * sa
                     : A0 + (size_t)ga * sa) + gsw;
    } else {
      gptr[c] = B + (size_t)(bn + row) * sb + gsw;
    }
  }
  auto STAGE = [&](int buf, int k0) {
#pragma unroll
    for (int c = 0; c < GPW; ++c) {
      luint* dst = isA[c] ? (luint*)&As[buf][row8[c]][0] : (luint*)&Bs[buf][row8[c]][0];
      __builtin_amdgcn_global_load_lds((guint*)(gptr[c] + k0), dst, 16, 0, 0);
    }
  };
  f32x4 acc[MF][4] = {};
  const int nt = Kd >> 6;
  STAGE(0, 0);
  __syncthreads();
  for (int ti = 0; ti < nt; ++ti) {
    const int cur = ti & 1;
    if (ti + 1 < nt) STAGE(cur ^ 1, (ti + 1) << 6);
#pragma unroll
    for (int ks = 0; ks < 2; ++ks) {
      short8 af[MF], bf[4];
#pragma unroll
      for (int x = 0; x < MF; ++x) {
        const int ra = wm + x * 16 + lrow;
        af[x] = *(const short8*)((const u16*)&As[cur][0][0] + ra * 64 + (((ks * 4 + lk) ^ (ra & 7)) * 8));
      }
#pragma unroll
      for (int x = 0; x < 4; ++x) {
        const int rb = wn + x * 16 + lrow;
        bf[x] = *(const short8*)((const u16*)&Bs[cur][0][0] + rb * 64 + (((ks * 4 + lk) ^ (rb & 7)) * 8));
      }
#pragma unroll
      for (int mi = 0; mi < MF; ++mi)
#pragma unroll
        for (int ni = 0; ni < 4; ++ni)
          acc[mi][ni] = __builtin_amdgcn_mfma_f32_16x16x32_bf16(af[mi], bf[ni], acc[mi][ni], 0, 0, 0);
    }
    __syncthreads();
  }
  const size_t row0 = bm + wm + lk * 4;
  const size_t col0 = bn + wn + lrow;
#pragma unroll
  for (int mi = 0; mi < MF; ++mi)
#pragma unroll
    for (int r = 0; r < 4; ++r) {
      const size_t row = row0 + mi * 16 + r;
#pragma unroll
      for (int ni = 0; ni < 4; ++ni) {
        float v = acc[mi][ni][r];
        if (BIAS) v += bias[col0 + ni * 16];
        if (RELU) v = fmaxf(v, 0.0f);
        if (OUTBF) ((u16*)Cp)[row * sc + col0 + ni * 16] = f2b(v);
        else       ((float*)Cp)[row * sc + col0 + ni * 16] = v;
      }
    }
}

// ---------------- BD GEMM, rel-shift folded into store, q-bias fused ----------------
// BDs[slice][i][j] = (q_i + rrb) . r_s  with j = s + i - 511 (stored iff j >= 0).
__global__ __launch_bounds__(256) void bd_gemm(
    const u16* __restrict__ qkvb, const u16* __restrict__ B,
    const float* __restrict__ rrb, u16* __restrict__ S)
{
  __shared__ u16 As[128][40];
  __shared__ u16 Bs[128][40];
  const int z = blockIdx.z, zb = z & 3, zn = z >> 2;
  const u16* Ab = qkvb + ((size_t)(QLEN * BATCH) + zb) * (3 * ND) + zn * 64;  // q rows, stride B*3ND
  const u16* Bb = B + zn * 64;                                               // rb [s][nd]
  u16* Sb = S + (size_t)(zn * 4 + zb) * 524288;
  const int bm = blockIdx.x * 128, bn = blockIdx.y * 128;
  const int t = threadIdx.x, wave = t >> 6, lane = t & 63;
  const int wm = (wave >> 1) * 64, wn = (wave & 1) * 64;
  const int lrow = lane & 15, lk = lane >> 4;
  const int srow = t >> 2, skc = (t & 3) * 8;
  f32x4 acc[4][4] = {};
  for (int k0 = 0; k0 < 64; k0 += 32) {
    union { u16 u[8]; float4 v; } a0, a1;
    a0.v = *(const float4*)(Ab + (size_t)(bm + srow) * (BATCH * 3 * ND) + k0 + skc);
    a1.v = *(const float4*)(Ab + (size_t)(bm + srow + 64) * (BATCH * 3 * ND) + k0 + skc);
#pragma unroll
    for (int e = 0; e < 8; ++e) {
      const float bias = rrb[zn * 64 + k0 + skc + e];
      a0.u[e] = f2b(b2f(a0.u[e]) + bias);
      a1.u[e] = f2b(b2f(a1.u[e]) + bias);
    }
    const float4 b0 = *(const float4*)(Bb + (size_t)(bn + srow) * 1024 + k0 + skc);
    const float4 b1 = *(const float4*)(Bb + (size_t)(bn + srow + 64) * 1024 + k0 + skc);
    __syncthreads();
    *(float4*)&As[srow][skc] = a0.v; *(float4*)&As[srow + 64][skc] = a1.v;
    *(float4*)&Bs[srow][skc] = b0;   *(float4*)&Bs[srow + 64][skc] = b1;
    __syncthreads();
    short8 af[4], bf[4];
#pragma unroll
    for (int x = 0; x < 4; ++x) af[x] = *(const short8*)&As[wm + x * 16 + lrow][lk * 8];
#pragma unroll
    for (int x = 0; x < 4; ++x) bf[x] = *(const short8*)&Bs[wn + x * 16 + lrow][lk * 8];
#pragma unroll
    for (int mi = 0; mi < 4; ++mi)
#pragma unroll
      for (int ni = 0; ni < 4; ++ni)
        acc[mi][ni] = __builtin_amdgcn_mfma_f32_16x16x32_bf16(af[mi], bf[ni], acc[mi][ni], 0, 0, 0);
  }
  const int row0 = bm + wm + lk * 4;
  const int col0 = bn + wn + lrow;
#pragma unroll
  for (int mi = 0; mi < 4; ++mi)
#pragma unroll
    for (int r = 0; r < 4; ++r) {
      const int row = row0 + mi * 16 + r;
#pragma unroll
      for (int ni = 0; ni < 4; ++ni) {
        const int j = col0 + ni * 16 + row - 511;
        if (j >= 0) Sb[(size_t)row * 1024 + j] = f2b(acc[mi][ni][r]);
      }
    }
}

// ---------------- V transpose: qkv V -> Vt[b][n][d][j] ----------------
__global__ __launch_bounds__(256) void vtrans_kernel(
    const u16* __restrict__ qkvb, u16* __restrict__ Vt)
{
  __shared__ u16 T[64][72];
  const int j0 = blockIdx.x * 64;
  const int bn = blockIdx.y, b = bn >> 4, n = bn & 15;
  const int t = threadIdx.x;
  const int jl = t >> 3, ch = t & 7;
#pragma unroll
  for (int p = 0; p < 2; ++p) {
    const int jj = p * 32 + jl;
    const float4 v = *(const float4*)(qkvb + ((size_t)(j0 + jj) * BATCH + b) * (3 * ND)
                                      + 2 * ND + n * 64 + ch * 8);
    *(float4*)&T[jj][ch * 8] = v;
  }
  __syncthreads();
#pragma unroll
  for (int p = 0; p < 2; ++p) {
    const int dd = p * 32 + jl;
    union { u16 u[8]; float4 v; } o;
#pragma unroll
    for (int e = 0; e < 8; ++e) o.u[e] = T[ch * 8 + e][dd];
    *(float4*)(Vt + ((size_t)(b * 16 + n) * 64 + dd) * 1024 + j0 + ch * 8) = o.v;
  }
}

// -------- flash attention: QBLK=128, 8 waves, q-bias fused, pipelined --------
__global__ __launch_bounds__(512) void flash_attn(
    const u16* __restrict__ qkvb, const u16* __restrict__ Vt,
    const u16* __restrict__ BDs, const float* __restrict__ rwb,
    u16* __restrict__ O)
{
  __shared__ u16 qs[128][72];
  __shared__ u16 ks[2][64][72];
  __shared__ u16 vs[2][64][72];
  __shared__ u16 ps[8][16][72];
  const int i0 = blockIdx.x * 128;
  const int n = blockIdx.y, b = blockIdx.z;
  const int t = threadIdx.x, wave = t >> 6, lane = t & 63;
  const int lrow = lane & 15, lk = lane >> 4;
  const int ilb = wave * 16 + lk * 4;
  // Q staging with r_w_bias fused (f32 add before bf16 round)
  {
    const int qr = t >> 2, qc = (t & 3) * 16;
    const u16* qsrc = qkvb + ((size_t)(QLEN + i0 + qr) * BATCH + b) * (3 * ND) + n * 64 + qc;
#pragma unroll
    for (int p = 0; p < 2; ++p) {
      union { u16 u[8]; float4 v; } q8;
      q8.v = *(const float4*)(qsrc + p * 8);
#pragma unroll
      for (int e = 0; e < 8; ++e)
        q8.u[e] = f2b(b2f(q8.u[e]) + rwb[n * 64 + qc + p * 8 + e]);
      *(float4*)&qs[qr][qc + p * 8] = q8.v;
    }
  }
  const u16* bd = BDs + ((size_t)(n * 4 + b) * QLEN + i0) * 1024;
  const int ntiles = blockIdx.x * 2 + 10;
  const int jr = t >> 3, jc = (t & 7) * 8;

  float4 kr, vr;
  u16 bdn[16], bdc[16];
  auto LOADT = [&](int j0) {
    kr = *(const float4*)(qkvb + ((size_t)(j0 + jr) * BATCH + b) * (3 * ND) + ND + n * 64 + jc);
    vr = *(const float4*)(Vt + ((size_t)(b * 16 + n) * 64 + jr) * 1024 + j0 + jc);
#pragma unroll
    for (int nf = 0; nf < 4; ++nf)
#pragma unroll
      for (int r = 0; r < 4; ++r)
        bdn[nf * 4 + r] = bd[(size_t)(ilb + r) * 1024 + j0 + nf * 16 + lrow];
  };
  auto WRITET = [&](int buf) {
    *(float4*)&ks[buf][jr][jc] = kr;
    *(float4*)&vs[buf][jr][jc] = vr;
  };

  LOADT(0);
  WRITET(0);
#pragma unroll
  for (int e = 0; e < 16; ++e) bdc[e] = bdn[e];

  f32x4 o[4] = {};
  float m[4] = {-INFINITY, -INFINITY, -INFINITY, -INFINITY};
  float l[4] = {0.0f, 0.0f, 0.0f, 0.0f};

  for (int jt = 0; jt < ntiles; ++jt) {
    const int cur = jt & 1;
    const int j0 = jt * 64;
    __syncthreads();
    if (jt + 1 < ntiles) LOADT(j0 + 64);
    f32x4 s[4] = {};
    const short8 aq0 = *(const short8*)&qs[wave * 16 + lrow][lk * 8];
    const short8 aq1 = *(const short8*)&qs[wave * 16 + lrow][32 + lk * 8];
#pragma unroll
    for (int nf = 0; nf < 4; ++nf) {
      const short8 b0 = *(const short8*)&ks[cur][nf * 16 + lrow][lk * 8];
      const short8 b1 = *(const short8*)&ks[cur][nf * 16 + lrow][32 + lk * 8];
      s[nf] = __builtin_amdgcn_mfma_f32_16x16x32_bf16(aq0, b0, s[nf], 0, 0, 0);
      s[nf] = __builtin_amdgcn_mfma_f32_16x16x32_bf16(aq1, b1, s[nf], 0, 0, 0);
    }
    float sv[4][4];
#pragma unroll
    for (int nf = 0; nf < 4; ++nf)
#pragma unroll
      for (int r = 0; r < 4; ++r) {
        const int ig = i0 + ilb + r;
        const int jg = j0 + nf * 16 + lrow;
        const float val = (s[nf][r] + b2f(bdc[nf * 4 + r])) * 0.125f;
        sv[nf][r] = (jg <= ig + MLEN) ? val : -INFINITY;
      }
#pragma unroll
    for (int r = 0; r < 4; ++r) {
      float mt = fmaxf(fmaxf(sv[0][r], sv[1][r]), fmaxf(sv[2][r], sv[3][r]));
#pragma unroll
      for (int dx = 1; dx < 16; dx <<= 1) mt = fmaxf(mt, __shfl_xor(mt, dx));
      const float mnew = fmaxf(m[r], mt);
      const float alpha = __expf(m[r] - mnew);
      float ls = 0.0f;
#pragma unroll
      for (int nf = 0; nf < 4; ++nf) {
        const float pv = __expf(sv[nf][r] - mnew);
        sv[nf][r] = pv;
        ls += pv;
      }
#pragma unroll
      for (int dx = 1; dx < 16; dx <<= 1) ls += __shfl_xor(ls, dx);
      l[r] = l[r] * alpha + ls;
      m[r] = mnew;
#pragma unroll
      for (int nf = 0; nf < 4; ++nf) o[nf][r] *= alpha;
    }
#pragma unroll
    for (int nf = 0; nf < 4; ++nf)
#pragma unroll
      for (int r = 0; r < 4; ++r)
        ps[wave][lk * 4 + r][nf * 16 + lrow] = f2b(sv[nf][r]);
    asm volatile("s_waitcnt lgkmcnt(0)" ::: "memory");
    __builtin_amdgcn_sched_barrier(0);
    const short8 pa0 = *(const short8*)&ps[wave][lrow][lk * 8];
    const short8 pa1 = *(const short8*)&ps[wave][lrow][32 + lk * 8];
#pragma unroll
    for (int nf = 0; nf < 4; ++nf) {
      const short8 b0 = *(const short8*)&vs[cur][nf * 16 + lrow][lk * 8];
      const short8 b1 = *(const short8*)&vs[cur][nf * 16 + lrow][32 + lk * 8];
      o[nf] = __builtin_amdgcn_mfma_f32_16x16x32_bf16(pa0, b0, o[nf], 0, 0, 0);
      o[nf] = __builtin_amdgcn_mfma_f32_16x16x32_bf16(pa1, b1, o[nf], 0, 0, 0);
    }
    if (jt + 1 < ntiles) {
      WRITET(cur ^ 1);
#pragma unroll
      for (int e = 0; e < 16; ++e) bdc[e] = bdn[e];
    }
  }
#pragma unroll
  for (int r = 0; r < 4; ++r) {
    const float inv = 1.0f / l[r];
    const size_t ig = i0 + ilb + r;
#pragma unroll
    for (int nf = 0; nf < 4; ++nf)
      O[(ig * BATCH + b) * ND + n * 64 + nf * 16 + lrow] = f2b(o[nf][r] * inv);
  }
}

// ---------------- fused residual + LayerNorm ----------------
__global__ __launch_bounds__(256) void ln_residual_kernel(
    float* __restrict__ h, u16* __restrict__ hb, const float* __restrict__ delta,
    const float* __restrict__ g, const float* __restrict__ bb)
{
  const int row = blockIdx.x, t = threadIdx.x;
  __shared__ float xs[DMODEL];
  __shared__ float red[256];
  float s = 0.0f;
  for (int d = t; d < DMODEL; d += 256) {
    const float v = h[(size_t)row * DMODEL + d] + delta[(size_t)row * DMODEL + d];
    xs[d] = v;
    s += v;
  }
  red[t] = s;
  __syncthreads();
  for (int w = 128; w > 0; w >>= 1) {
    if (t < w) red[t] += red[t + w];
    __syncthreads();
  }
  const float mean = red[0] * (1.0f / DMODEL);
  __syncthreads();
  float vs = 0.0f;
  for (int d = t; d < DMODEL; d += 256) {
    const float dv = xs[d] - mean;
    vs = fmaf(dv, dv, vs);
  }
  red[t] = vs;
  __syncthreads();
  for (int w = 128; w > 0; w >>= 1) {
    if (t < w) red[t] += red[t + w];
    __syncthreads();
  }
  const float rstd = rsqrtf(red[0] * (1.0f / DMODEL) + 1e-5f);
  for (int d = t; d < DMODEL; d += 256) {
    const float o = (xs[d] - mean) * rstd * g[d] + bb[d];
    h[(size_t)row * DMODEL + d] = o;
    hb[(size_t)row * DMODEL + d] = f2b(o);
  }
}

// ---------------- output transpose ----------------
__global__ __launch_bounds__(256) void out_kernel(
    const float* __restrict__ h, float* __restrict__ out)
{
  const int q = blockIdx.x, b = blockIdx.y, t = threadIdx.x;
  const float4* src = (const float4*)(h + ((size_t)q * BATCH + b) * DMODEL);
  float4* dst = (float4*)(out + ((size_t)b * QLEN + q) * DMODEL);
  dst[t] = src[t];
}

extern "C" void kernel_launch(void* const* d_in, const int* in_sizes, int n_in,
                              void* d_out, int out_size, void* d_ws, size_t ws_size,
                              hipStream_t stream)
{
  const int*   tok  = (const int*)d_in[0];
  const float* mems = (const float*)d_in[1];
  const float* wemb = (const float*)d_in[2];
  const float* qkvw = (const float*)d_in[3];
  const float* ow   = (const float*)d_in[4];
  const float* rw   = (const float*)d_in[5];
  const float* rwb  = (const float*)d_in[6];
  const float* rrb  = (const float*)d_in[7];
  const float* ln1g = (const float*)d_in[8];
  const float* ln1b = (const float*)d_in[9];
  const float* ffw1 = (const float*)d_in[10];
  const float* ffb1 = (const float*)d_in[11];
  const float* ffw2 = (const float*)d_in[12];
  const float* ffb2 = (const float*)d_in[13];
  const float* ln2g = (const float*)d_in[14];
  const float* ln2b = (const float*)d_in[15];

  float* h      = (float*)d_ws;               // [2048][1024] f32
  u16* S        = (u16*)(h + 2097152);        // BDshifted [64][512][1024] bf16 (64 MB)
  float* tmp    = (float*)S;                  // alias (BD dead after flash)
  u16* h_bf     = S + 33554432;
  u16* qkv_bf   = h_bf + 2097152;             // [4096][3072]
  u16* ffh_bf   = qkv_bf;                     // alias (qkv dead after attention)
  u16* pe_bf    = qkv_bf + 12582912;
  u16* rb_bf    = pe_bf + 1048576;
  u16* Vt       = rb_bf + 1048576;            // [4][16][64][1024]
  u16* vec_bf   = Vt + 4194304;               // [2048][1024]
  u16* mems_bf  = vec_bf + 2097152;           // [4][2048][1024]
  u16* wq = mems_bf + 8388608;                // [4][3072][1024]
  u16* wo = wq + 12582912;
  u16* wr = wo + 4194304;
  u16* w1 = wr + 4194304;                     // [4][4096][1024]
  u16* w2 = w1 + 16777216;                    // [4][1024][4096]

  embed_kernel<<<dim3(QLEN, BATCH), 256, 0, stream>>>(tok, wemb, h, h_bf);
  posemb_kernel<<<KLEN, 256, 0, stream>>>(pe_bf);

#define CONV(src, dst, n) conv_bf16<<<(n) / 2048, 256, 0, stream>>>(src, dst, (n) / 8)
  CONV(mems, mems_bf, 8388608);
  CONV(qkvw, wq, 12582912);
  CONV(ow,   wo, 4194304);
  CONV(rw,   wr, 4194304);
  CONV(ffw1, w1, 16777216);
  CONV(ffw2, w2, 16777216);

  for (int l = 0; l < NLAYER; ++l) {
    // qkv = cat(mems_bf[l], h_bf) @ qkv_w^T  (bf16 out)
    mgemm3<4, 1, 0, 0><<<dim3(32, 24), 256, 0, stream>>>(
        mems_bf + (size_t)l * 2097152, h_bf, 2048,
        wq + (size_t)l * 3145728, qkv_bf, nullptr, 1024, 1024, 1024, 3072);
    // r = pe @ r_w^T  (bf16 out)
    mgemm3<2, 1, 0, 0><<<dim3(16, 8), 256, 0, stream>>>(
        pe_bf, nullptr, 0, wr + (size_t)l * 1048576, rb_bf, nullptr,
        1024, 1024, 1024, 1024);

    vtrans_kernel<<<dim3(16, 64), 256, 0, stream>>>(qkv_bf, Vt);

    // BDshifted[n*4+b][i][j] = (q_i + rrb) . r_{j-i+511}
    bd_gemm<<<dim3(4, 8, 64), 256, 0, stream>>>(
        qkv_bf, rb_bf, rrb + (size_t)l * ND, S);

    flash_attn<<<dim3(4, 16, 4), 512, 0, stream>>>(
        qkv_bf, Vt, S, rwb + (size_t)l * ND, vec_bf);

    // o-proj (f32 out into tmp)
    mgemm3<2, 0, 0, 0><<<dim3(32, 8), 256, 0, stream>>>(
        vec_bf, nullptr, 0, wo + (size_t)l * 1048576, tmp, nullptr,
        1024, 1024, 1024, 1024);
    ln_residual_kernel<<<2048, 256, 0, stream>>>(
        h, h_bf, tmp, ln1g + (size_t)l * DMODEL, ln1b + (size_t)l * DMODEL);
    // FFN1 (bf16 out, bias+relu)
    mgemm3<4, 1, 1, 1><<<dim3(16, 32), 256, 0, stream>>>(
        h_bf, nullptr, 0, w1 + (size_t)l * 4194304, ffh_bf,
        ffb1 + (size_t)l * DINNER, 1024, 1024, 1024, 4096);
    // FFN2 (f32 out, bias)
    mgemm3<2, 0, 0, 1><<<dim3(32, 8), 256, 0, stream>>>(
        ffh_bf, nullptr, 0, w2 + (size_t)l * 4194304, tmp,
        ffb2 + (size_t)l * DMODEL, 4096, 4096, 4096, 1024);
    ln_residual_kernel<<<2048, 256, 0, stream>>>(
        h, h_bf, tmp, ln2g + (size_t)l * DMODEL, ln2b + (size_t)l * DMODEL);
  }

  out_kernel<<<dim3(QLEN, BATCH), 256, 0, stream>>>(h, (float*)d_out);
}